// Round 3
// baseline (168.277 us; speedup 1.0000x reference)
//
#include <hip/hip_runtime.h>
#include <hip/hip_bf16.h>
#include <cstdint>

// ---------------------------------------------------------------------------
// CausalSelfAttention: x@Wqkv+b -> heads -> causal flash attn -> @Wproj+b
// B=2 T=2048 C=1024 H=16 Dh=64.
// R13: attn rebalanced + VALU-thinned.
//  - Grid 2048 x 128thr: one 32-row q-group per block, 2 parity waves.
//    Heavy groups (g32=63) dispatch FIRST (LPT backfill); bh pinned to XCD
//    (bid&7) so each XCD's 4 bh keep KF+VF (2MB) L2-resident.
//    (R12 was 4-wave blocks pairing u/63-u: per-wave tiles ranged 1..16 and
//    half the waves idled at the barrier -> 15% occupancy measured.)
//  - l-sum via ones-column MFMA: accL = mfma(P_frag, ones) -- the MFMA's
//    k-contraction does the cross-quad reduce in HW; epilogue shfl chain
//    gone; l is summed from the SAME bf16 P that PV uses (self-consistent).
//  - P pack via v_cvt_pk_bf16_f32 (1 op/pair, no builtin -> inline asm).
//  - Tile loop unrolled x2 (kA/kB alternate) -> no 32-v_mov K rotate.
// R12 (kept): gemm_qkv 256x192 3-phase pipelined, 256-block full coverage,
//  LDS XOR-swizzle (bank conflicts 3.1M->0), counted vmcnt(5), setprio.
// HARD-WON NOTES:
//  - R7: __launch_bounds__(256,4) forced VGPR=64 -> 380MB scratch spills.
//  - R8: V-frag loads after softmax doubled per-tile exposed latency.
//  - R10: K-frags pipelined one tile ahead (depth-2); VGPR must stay <=128
//    (129+ halves waves/SIMD).
// ---------------------------------------------------------------------------

using u16 = unsigned short;
using u32 = unsigned int;

typedef __bf16 bf16x8 __attribute__((ext_vector_type(8)));
typedef float f32x4 __attribute__((ext_vector_type(4)));

#define AS1 __attribute__((address_space(1)))
#define AS3 __attribute__((address_space(3)))

__device__ __forceinline__ u16 f2bf(float f) {
  u32 u = __float_as_uint(f);
  u += 0x7fffu + ((u >> 16) & 1u);   // RTNE
  return (u16)(u >> 16);
}
__device__ __forceinline__ u32 cvtpk(float a, float b) {
  u32 r;
  asm("v_cvt_pk_bf16_f32 %0, %1, %2" : "=v"(r) : "v"(a), "v"(b));
  return r;
}

// ---------------- prep: cvt x->bf16 (blocks 0..4095) + W transposes ---------
__global__ __launch_bounds__(256) void prep(const float* __restrict__ x,
                                            u16* __restrict__ xb,
                                            const float* __restrict__ W0,
                                            u16* __restrict__ T0,
                                            const float* __restrict__ W1,
                                            u16* __restrict__ T1) {
  const int bx = blockIdx.x;
  const int tid = threadIdx.x;
  if (bx < 4096) {
    const int i = bx * 256 + tid;
    float4 v = ((const float4*)x)[i];
    ushort4 o;
    o.x = f2bf(v.x); o.y = f2bf(v.y); o.z = f2bf(v.z); o.w = f2bf(v.w);
    ((ushort4*)xb)[i] = o;
    return;
  }
  __shared__ float t[32][33];
  const int idx = bx - 4096;          // 128 n-tiles x 32 k-tiles
  const int bxx = idx & 127, by = idx >> 7;
  const float* W; u16* Wt; int N, n0;
  if (bxx < 96) { W = W0; Wt = T0; N = 3072; n0 = bxx * 32; }
  else          { W = W1; Wt = T1; N = 1024; n0 = (bxx - 96) * 32; }
  const int k0 = by * 32;
  const int tx = tid & 31, ty = tid >> 5;
#pragma unroll
  for (int i = 0; i < 4; ++i)
    t[ty + i * 8][tx] = W[(size_t)(k0 + ty + i * 8) * N + n0 + tx];
  __syncthreads();
#pragma unroll
  for (int i = 0; i < 4; ++i)
    Wt[(size_t)(n0 + ty + i * 8) * 1024 + k0 + tx] = f2bf(t[tx][ty + i * 8]);
}

// ---------------- QKV GEMM: 256x192 3-phase pipelined -----------------------
// n<1024: Q (scaled by cs) -> qb[4096][1024]
// 1024<=n<2048: K -> KF fragment order [bh][kt][m][hh][lane][8]
// n>=2048:     V -> VF fragment order [bh][kt][hh][di][lane][8] (k-permuted)
#define MFMA16 __builtin_amdgcn_mfma_f32_16x16x32_bf16

__global__ __launch_bounds__(512, 2) void gemm_qkv(const u16* __restrict__ A,
                                                   const u16* __restrict__ Bt,
                                                   const float* __restrict__ bias,
                                                   u16* __restrict__ qb,
                                                   u16* __restrict__ KF,
                                                   u16* __restrict__ VF,
                                                   float sc_val) {
  constexpr int NT = 16;                    // K=1024 / BK=64
  constexpr int BUFO = 7 * 4096;            // u16 per buffer (7 chunks)
  __shared__ __align__(16) u16 sm[2 * BUFO];  // 112 KiB

  const int tid  = threadIdx.x;
  const int lane = tid & 63;
  const int w    = tid >> 6;          // 0..7
  const int quad = lane >> 4;
  const int l15  = lane & 15;

  // block -> tile: XCD-bijective (256 blocks = 8 XCD x 32), 4x8 region/XCD
  const int bid = blockIdx.x;
  const int xcd = bid & 7, c = bid >> 3;         // c 0..31
  const int mt = (xcd >> 1) * 4 + (c & 3);       // 0..15
  const int nt = (xcd & 1) * 8 + (c >> 2);       // 0..15
  const int bm = mt * 256, bn = nt * 192;

  const int wr = (w >> 2) * 128;      // wave rows (0/128)
  const int wc = (w & 3) * 48;        // wave cols (0/48/96/144)

  // ---- staging: thread writes 16B linearly at chunk + tid*16.
  // LDS row = tid>>3, granule = tid&7; source granule = (tid&7)^(row&7).
  const int srow = tid >> 3;
  const int scol = (((tid & 7) ^ ((tid >> 3) & 7)) << 3);

#define STAGEA(ch, ktile, bufo)                                                 \
  __builtin_amdgcn_global_load_lds(                                             \
      (AS1 const void*)(A + (size_t)(bm + (ch) * 64 + srow) * 1024 +            \
                        ((ktile) << 6) + scol),                                 \
      (AS3 void*)(sm + (bufo) + (ch) * 4096 + tid * 8), 16, 0, 0)
#define STAGEB(ch, ktile, bufo)                                                 \
  __builtin_amdgcn_global_load_lds(                                             \
      (AS1 const void*)(Bt + (size_t)(bn + (ch) * 64 + srow) * 1024 +           \
                        ((ktile) << 6) + scol),                                 \
      (AS3 void*)(sm + (bufo) + (4 + (ch)) * 4096 + tid * 8), 16, 0, 0)

  // ---- ds-read bases (swizzled granule; row&7 == l15&7 everywhere)
  const int ca = (w >> 2) * 2;        // A chunk base: 0 or 2
  int abase_lo[4], abase_hi[4], bbase[3];
#pragma unroll
  for (int mi = 0; mi < 4; ++mi) {
    abase_lo[mi] = (ca + 0) * 4096 + (mi * 16 + l15) * 64;
    abase_hi[mi] = (ca + 1) * 4096 + (mi * 16 + l15) * 64;
  }
#pragma unroll
  for (int ni = 0; ni < 3; ++ni) {
    const int rb = wc + ni * 16 + l15;            // 0..191
    bbase[ni] = (4 + (rb >> 6)) * 4096 + (rb & 63) * 64;
  }
  const int sw0 = ((quad ^ (l15 & 7)) << 3);
  const int sw1 = sw0 ^ 32;

  // ---- prologue: kt0 all 7 -> buf0; kt1 B0B1,B2A0A1 -> buf1
  STAGEA(0, 0, 0); STAGEA(1, 0, 0); STAGEA(2, 0, 0); STAGEA(3, 0, 0);
  STAGEB(0, 0, 0); STAGEB(1, 0, 0); STAGEB(2, 0, 0);
  STAGEB(0, 1, BUFO); STAGEB(1, 1, BUFO);
  STAGEB(2, 1, BUFO); STAGEA(0, 1, BUFO); STAGEA(1, 1, BUFO);
  asm volatile("s_waitcnt vmcnt(5)" ::: "memory");  // kt0 landed; kt1's 5 fly
  __builtin_amdgcn_s_barrier();

  f32x4 acc[8][3] = {};
  bf16x8 alo[4][2], ahi[4][2], b[3][2];

#pragma unroll 2
  for (int j = 0; j < NT; ++j) {
    const int bo  = (j & 1) * BUFO;
    const int nbo = bo ^ BUFO;
    const u16* smb = sm + bo;

    // ---------- phase 0: ds a_lo + b0,b1; stage A2A3(j+1); MFMA mi0-3 x ni0,1
#pragma unroll
    for (int mi = 0; mi < 4; ++mi) {
      alo[mi][0] = *(const bf16x8*)(smb + abase_lo[mi] + sw0);
      alo[mi][1] = *(const bf16x8*)(smb + abase_lo[mi] + sw1);
    }
#pragma unroll
    for (int ni = 0; ni < 2; ++ni) {
      b[ni][0] = *(const bf16x8*)(smb + bbase[ni] + sw0);
      b[ni][1] = *(const bf16x8*)(smb + bbase[ni] + sw1);
    }
    if (j + 1 < NT) { STAGEA(2, j + 1, nbo); STAGEA(3, j + 1, nbo); }
    __builtin_amdgcn_s_barrier();
    asm volatile("s_waitcnt lgkmcnt(0)" ::: "memory");
    __builtin_amdgcn_s_setprio(1);
#pragma unroll
    for (int mi = 0; mi < 4; ++mi)
#pragma unroll
      for (int ni = 0; ni < 2; ++ni) {
        acc[mi][ni] = MFMA16(alo[mi][0], b[ni][0], acc[mi][ni], 0, 0, 0);
        acc[mi][ni] = MFMA16(alo[mi][1], b[ni][1], acc[mi][ni], 0, 0, 0);
      }
    __builtin_amdgcn_s_setprio(0);
    __builtin_amdgcn_s_barrier();

    // ---------- phase 1: ds a_hi + b2; stage B0B1(j+2); MFMA mi0-3xni2 + mi4-7xni0
#pragma unroll
    for (int mi = 0; mi < 4; ++mi) {
      ahi[mi][0] = *(const bf16x8*)(smb + abase_hi[mi] + sw0);
      ahi[mi][1] = *(const bf16x8*)(smb + abase_hi[mi] + sw1);
    }
    b[2][0] = *(const bf16x8*)(smb + bbase[2] + sw0);
    b[2][1] = *(const bf16x8*)(smb + bbase[2] + sw1);
    if (j + 2 < NT) { STAGEB(0, j + 2, bo); STAGEB(1, j + 2, bo); }
    __builtin_amdgcn_s_barrier();
    asm volatile("s_waitcnt lgkmcnt(0)" ::: "memory");
    __builtin_amdgcn_s_setprio(1);
#pragma unroll
    for (int mi = 0; mi < 4; ++mi) {
      acc[mi][2] = MFMA16(alo[mi][0], b[2][0], acc[mi][2], 0, 0, 0);
      acc[mi][2] = MFMA16(alo[mi][1], b[2][1], acc[mi][2], 0, 0, 0);
      acc[4 + mi][0] = MFMA16(ahi[mi][0], b[0][0], acc[4 + mi][0], 0, 0, 0);
      acc[4 + mi][0] = MFMA16(ahi[mi][1], b[0][1], acc[4 + mi][0], 0, 0, 0);
    }
    __builtin_amdgcn_s_setprio(0);
    __builtin_amdgcn_s_barrier();

    // ---------- phase 2: stage B2,A0,A1(j+2); MFMA mi4-7 x ni1,2; vmcnt(5)
    if (j + 2 < NT) { STAGEB(2, j + 2, bo); STAGEA(0, j + 2, bo); STAGEA(1, j + 2, bo); }
    __builtin_amdgcn_s_barrier();
    __builtin_amdgcn_s_setprio(1);
#pragma unroll
    for (int mi = 0; mi < 4; ++mi)
#pragma unroll
      for (int ni = 1; ni < 3; ++ni) {
        acc[4 + mi][ni] = MFMA16(ahi[mi][0], b[ni][0], acc[4 + mi][ni], 0, 0, 0);
        acc[4 + mi][ni] = MFMA16(ahi[mi][1], b[ni][1], acc[4 + mi][ni], 0, 0, 0);
      }
    __builtin_amdgcn_s_setprio(0);
    if (j + 2 < NT)
      asm volatile("s_waitcnt vmcnt(5)" ::: "memory"); // drains A2A3(j+1)+older
    else
      asm volatile("s_waitcnt vmcnt(0)" ::: "memory"); // tail drain
    __builtin_amdgcn_s_barrier();
  }
#undef STAGEA
#undef STAGEB

  // ---- epilogue: per-ni region branch (192-wide blocks straddle Q/K/V) ----
  const int crow0 = bm + wr + (quad << 2);
  const int ccol0 = bn + wc + l15;
#pragma unroll
  for (int ni = 0; ni < 3; ++ni) {
    const int n = ccol0 + ni * 16;
    const float bv = bias[n];
    if (n < 1024) {                     // ---- Q (scaled) ----
#pragma unroll
      for (int mi = 0; mi < 8; ++mi) {
        const int m0 = crow0 + mi * 16;
#pragma unroll
        for (int r = 0; r < 4; ++r)
          qb[(size_t)(m0 + r) * 1024 + n] = f2bf((acc[mi][ni][r] + bv) * sc_val);
      }
    } else if (n < 2048) {              // ---- K fragment order ----
      const int hk = (n - 1024) >> 6;
      const int d  = (n - 1024) & 63;
      const int hh = d >> 5, qd = (d >> 3) & 3, jj = d & 7;
#pragma unroll
      for (int mi = 0; mi < 8; ++mi) {
#pragma unroll
        for (int r = 0; r < 4; ++r) {
          const int t  = crow0 + mi * 16 + r;
          const int bb = t >> 11, tt = t & 2047;
          const int kt = tt >> 6, mm = (tt >> 4) & 3, l = tt & 15;
          KF[((size_t)((bb * 16 + hk) * 32 + kt) * 8 + mm * 2 + hh) * 512 +
             (qd * 16 + l) * 8 + jj] = f2bf(acc[mi][ni][r] + bv);
        }
      }
    } else {                            // ---- V fragment order (k-perm) ----
      const int hv = (n - 2048) >> 6;
      const int d  = (n - 2048) & 63;
      const int di = d >> 4, l = d & 15;
#pragma unroll
      for (int mi = 0; mi < 8; ++mi) {
#pragma unroll
        for (int r = 0; r < 4; ++r) {
          const int t  = crow0 + mi * 16 + r;
          const int bb = t >> 11, tt = t & 2047;
          const int kt = tt >> 6, to = tt & 63;
          const int mq = to >> 4, qd2 = (to >> 2) & 3, rr = to & 3;
          const int hh = mq >> 1, jj = (mq & 1) * 4 + rr;
          VF[((size_t)((bb * 16 + hv) * 32 + kt) * 8 + hh * 4 + di) * 512 +
             (qd2 * 16 + l) * 8 + jj] = f2bf(acc[mi][ni][r] + bv);
        }
      }
    }
  }
}

// ---------------- Proj GEMM: 128x64 tile, fp32 out --------------------------
__global__ __launch_bounds__(256) void gemm_proj(const u16* __restrict__ A,
                                                 const u16* __restrict__ Bt,
                                                 const float* __restrict__ bias,
                                                 float* __restrict__ C) {
  constexpr int BM = 128, BN = 64, BK = 32;
  constexpr int K = 1024, N = 1024;
  __shared__ __align__(16) u16 lA[BM * BK];
  __shared__ __align__(16) u16 lB[BN * BK];
  const int tid  = threadIdx.x;
  const int lane = tid & 63;
  const int wave = tid >> 6;
  const int bm = blockIdx.x * BM;
  const int bn = blockIdx.y * BN;
  const int wr = wave * 32;

  f32x4 acc[2][4] = {};

  const int f0 = (wave << 10) + (lane << 4);
  const int f1 = f0 + 4096;
  const int ar0 = f0 >> 6, ac0 = (f0 & 63) >> 1;
  const int ar1 = f1 >> 6, ac1 = (f1 & 63) >> 1;

  const int arow = wr + (lane & 15);
  const int brow = (lane & 15);
  const int kk   = (lane >> 4) << 3;

  for (int k0 = 0; k0 < K; k0 += BK) {
    __builtin_amdgcn_global_load_lds((AS1 const void*)(A + (size_t)(bm + ar0) * K + k0 + ac0),
                                     (AS3 void*)(lA + (wave << 9)), 16, 0, 0);
    __builtin_amdgcn_global_load_lds((AS1 const void*)(A + (size_t)(bm + ar1) * K + k0 + ac1),
                                     (AS3 void*)(lA + ((wave + 4) << 9)), 16, 0, 0);
    __builtin_amdgcn_global_load_lds((AS1 const void*)(Bt + (size_t)(bn + ar0) * K + k0 + ac0),
                                     (AS3 void*)(lB + (wave << 9)), 16, 0, 0);
    __syncthreads();

    bf16x8 af[2], bfr[4];
#pragma unroll
    for (int mi = 0; mi < 2; ++mi)
      af[mi] = *(const bf16x8*)&lA[(arow + mi * 16) * BK + kk];
#pragma unroll
    for (int ni = 0; ni < 4; ++ni)
      bfr[ni] = *(const bf16x8*)&lB[(brow + ni * 16) * BK + kk];
#pragma unroll
    for (int mi = 0; mi < 2; ++mi)
#pragma unroll
      for (int ni = 0; ni < 4; ++ni)
        acc[mi][ni] = __builtin_amdgcn_mfma_f32_16x16x32_bf16(af[mi], bfr[ni],
                                                              acc[mi][ni], 0, 0, 0);
    __syncthreads();
  }

  const int crow0 = bm + wr + ((lane >> 4) << 2);
  const int ccol0 = bn + (lane & 15);
#pragma unroll
  for (int ni = 0; ni < 4; ++ni) {
    const int n = ccol0 + ni * 16;
    const float bv = bias[n];
#pragma unroll
    for (int mi = 0; mi < 2; ++mi) {
      const int m0 = crow0 + mi * 16;
#pragma unroll
      for (int r = 0; r < 4; ++r)
        C[(size_t)(m0 + r) * N + n] = acc[mi][ni][r] + bv;
    }
  }
}

// ---------------- balanced pipelined MFMA flash attention -------------------
// grid 2048 flat x 128 threads (2 parity waves per 32-row q-group).
// bid: g32 = 63-((bid>>3)&63) -- heavy groups first (LPT backfill);
// bh = (bid&7) | ((bid>>9)<<3) -- XCD-pinned (4 bh per XCD, KV L2-resident).
// Per tile: V-frags at top; K-frags for kt+2 prefetched (depth-2, kA/kB
// alternate -- no register rotate).  Softmax: exp2 -> cvt_pk bf16 pack ->
// l via ones-column MFMA (HW cross-quad reduce, lane holds l for its rows).
__global__ __launch_bounds__(128) void attn_bal(const u16* __restrict__ qb,
                                                const u16* __restrict__ KF,
                                                const u16* __restrict__ VF,
                                                u16* __restrict__ out) {
  const int bid = blockIdx.x;
  const int g32 = 63 - ((bid >> 3) & 63);
  const int bh  = (bid & 7) | ((bid >> 9) << 3);
  const int b = bh >> 4, h = bh & 15;
  const int tid = threadIdx.x;
  const int lane = tid & 63;
  const int par  = tid >> 6;          // wave 0/1 = kt parity
  const int quad = lane >> 4;
  const int l15  = lane & 15;
  const int q0 = g32 * 32;
  const int ktmax = g32 >> 1;

  __shared__ float CB[64][41];        // [lane][32 accO + 8 accL], stride 41

  // Q B-frags, held all kernel
  const u16* qbase = qb + (size_t)b * 2048 * 1024 + h * 64;
  bf16x8 qf[2][2];
#pragma unroll
  for (int g = 0; g < 2; ++g)
#pragma unroll
    for (int hh = 0; hh < 2; ++hh)
      qf[g][hh] = *(const bf16x8*)(qbase + (size_t)(q0 + g * 16 + l15) * 1024 +
                                   hh * 32 + quad * 8);

  const size_t fb = (size_t)bh * 32 * 4096 + lane * 8;
  const u16* kfb = KF + fb;
  const u16* vfb = VF + fb;

  f32x4 accO[2][4] = {};              // [g][di]: q=quad*4+r, d=di*16+l15
  f32x4 accL[2] = {};                 // [g]: l for q=quad*4+r (all l15 equal)

  union { u32 u4[4]; bf16x8 v; } onesu;
  onesu.u4[0] = onesu.u4[1] = onesu.u4[2] = onesu.u4[3] = 0x3f803f80u;
  const bf16x8 onesf = onesu.v;       // bf16 1.0 x8

  // depth-2 K pipeline, two register sets (no rotate)
  bf16x8 kA[4][2], kB[4][2];
  {
    const u16* kp = kfb + (size_t)par * 4096;
#pragma unroll
    for (int m = 0; m < 4; ++m)
#pragma unroll
      for (int hh = 0; hh < 2; ++hh)
        kA[m][hh] = *(const bf16x8*)(kp + (m * 2 + hh) * 512);
  }

  auto tile = [&](int kt, bf16x8 (&KC)[4][2], bf16x8 (&KN)[4][2]) {
    // V-frags for current tile
    const u16* vp = vfb + (size_t)kt * 4096;
    bf16x8 vfr[2][4];
#pragma unroll
    for (int hh = 0; hh < 2; ++hh)
#pragma unroll
      for (int di = 0; di < 4; ++di)
        vfr[hh][di] = *(const bf16x8*)(vp + (hh * 4 + di) * 512);
    // K-frags for tile kt+2 (clamped) -> other register set
    const int ktn = (kt + 2 <= ktmax) ? kt + 2 : ktmax;
    const u16* kpn = kfb + (size_t)ktn * 4096;
#pragma unroll
    for (int m = 0; m < 4; ++m)
#pragma unroll
      for (int hh = 0; hh < 2; ++hh)
        KN[m][hh] = *(const bf16x8*)(kpn + (m * 2 + hh) * 512);

    const bool diag = (kt == ktmax);
    bf16x8 ap[2][2];
#pragma unroll
    for (int g = 0; g < 2; ++g) {
      f32x4 sT[4] = {};
#pragma unroll
      for (int m = 0; m < 4; ++m) {
        sT[m] = MFMA16(KC[m][0], qf[g][0], sT[m], 0, 0, 0);
        sT[m] = MFMA16(KC[m][1], qf[g][1], sT[m], 0, 0, 0);
      }
      float pv[4][4];
      if (diag) {                      // only the last tile pays mask ops
        const int qgl = q0 + g * 16 + l15;
#pragma unroll
        for (int m = 0; m < 4; ++m)
#pragma unroll
          for (int r = 0; r < 4; ++r) {
            const bool msk = (kt * 64 + m * 16 + quad * 4 + r) > qgl;
            pv[m][r] = msk ? 0.f : __builtin_amdgcn_exp2f(sT[m][r]);
          }
      } else {
#pragma unroll
        for (int m = 0; m < 4; ++m)
#pragma unroll
          for (int r = 0; r < 4; ++r)
            pv[m][r] = __builtin_amdgcn_exp2f(sT[m][r]);
      }
      union { u32 u4[4]; bf16x8 v; } t0, t1;
      t0.u4[0] = cvtpk(pv[0][0], pv[0][1]);
      t0.u4[1] = cvtpk(pv[0][2], pv[0][3]);
      t0.u4[2] = cvtpk(pv[1][0], pv[1][1]);
      t0.u4[3] = cvtpk(pv[1][2], pv[1][3]);
      t1.u4[0] = cvtpk(pv[2][0], pv[2][1]);
      t1.u4[1] = cvtpk(pv[2][2], pv[2][3]);
      t1.u4[2] = cvtpk(pv[3][0], pv[3][1]);
      t1.u4[3] = cvtpk(pv[3][2], pv[3][3]);
      ap[g][0] = t0.v;
      ap[g][1] = t1.v;
    }

    // O += P.V
#pragma unroll
    for (int hh = 0; hh < 2; ++hh)
#pragma unroll
      for (int di = 0; di < 4; ++di) {
        bf16x8 bv = vfr[hh][di];
#pragma unroll
        for (int g = 0; g < 2; ++g)
          accO[g][di] = MFMA16(ap[g][hh], bv, accO[g][di], 0, 0, 0);
      }
    // l += P.1 (MFMA does the cross-quad k-reduction)
#pragma unroll
    for (int g = 0; g < 2; ++g) {
      accL[g] = MFMA16(ap[g][0], onesf, accL[g], 0, 0, 0);
      accL[g] = MFMA16(ap[g][1], onesf, accL[g], 0, 0, 0);
    }
  };

  for (int kt = par; kt <= ktmax; ) {
    tile(kt, kA, kB); kt += 2;
    if (kt > ktmax) break;
    tile(kt, kB, kA); kt += 2;
  }

  // ---- exact parity combine (per-lane values) ----
  if (par) {
    float* cb = CB[lane];
#pragma unroll
    for (int g = 0; g < 2; ++g) {
#pragma unroll
      for (int di = 0; di < 4; ++di)
#pragma unroll
        for (int r = 0; r < 4; ++r)
          cb[g * 16 + di * 4 + r] = accO[g][di][r];
#pragma unroll
      for (int r = 0; r < 4; ++r)
        cb[32 + g * 4 + r] = accL[g][r];
    }
  }
  __syncthreads();
  if (!par) {
    const float* cb = CB[lane];
#pragma unroll
    for (int g = 0; g < 2; ++g) {
#pragma unroll
      for (int di = 0; di < 4; ++di)
#pragma unroll
        for (int r = 0; r < 4; ++r)
          accO[g][di][r] += cb[g * 16 + di * 4 + r];
#pragma unroll
      for (int r = 0; r < 4; ++r)
        accL[g][r] += cb[32 + g * 4 + r];
    }

#pragma unroll
    for (int g = 0; g < 2; ++g)
#pragma unroll
      for (int r = 0; r < 4; ++r) {
        const float inv = 1.f / accL[g][r];   // lane holds l for its own rows
        const int q = q0 + g * 16 + quad * 4 + r;
        u16* op = out + (size_t)(b * 2048 + q) * 1024 + h * 64 + l15;
#pragma unroll
        for (int di = 0; di < 4; ++di)
          op[di * 16] = f2bf(accO[g][di][r] * inv);
      }
  }
}

// ---------------------------------------------------------------------------
extern "C" void kernel_launch(void* const* d_in, const int* in_sizes, int n_in,
                              void* d_out, int out_size, void* d_ws, size_t ws_size,
                              hipStream_t stream) {
  const float* x     = (const float*)d_in[0];
  const float* Wqkv  = (const float*)d_in[1];
  const float* bqkv  = (const float*)d_in[2];
  const float* Wproj = (const float*)d_in[3];
  const float* bproj = (const float*)d_in[4];
  float* out = (float*)d_out;

  char* ws = (char*)d_ws;
  u16* xb     = (u16*)(ws);                 //  8 MB  x bf16 [4096,1024]
  u16* wqkvT  = (u16*)(ws + 8388608);       //  6 MB  Wqkv^T bf16 [3072,1024]
  u16* wprojT = (u16*)(ws + 14680064);      //  2 MB  Wproj^T bf16 [1024,1024]
  u16* qb     = (u16*)(ws + 16777216);      //  8 MB  Q bf16 [4096,1024] (pre-scaled)
  u16* KF     = (u16*)(ws + 25165824);      //  8 MB  K fragment-order
  u16* VF     = (u16*)(ws + 33554432);      //  8 MB  V fragment-order (k-perm)
  u16* att    = (u16*)(ws + 41943040);      //  8 MB  attn out bf16 [4096,1024]

  constexpr float cs = 0.18033688011f;      // log2(e)/8

  prep<<<8192, 256, 0, stream>>>(x, xb, Wqkv, wqkvT, Wproj, wprojT);

  gemm_qkv<<<dim3(256), 512, 0, stream>>>(xb, wqkvT, bqkv, qb, KF, VF, cs);

  attn_bal<<<dim3(2048), 128, 0, stream>>>(qb, KF, VF, att);

  gemm_proj<<<dim3(32, 16), 256, 0, stream>>>(att, wprojT, bproj, out);
}

// Round 4
// 159.277 us; speedup vs baseline: 1.0565x; 1.0565x over previous
//
#include <hip/hip_runtime.h>
#include <hip/hip_bf16.h>
#include <cstdint>

// ---------------------------------------------------------------------------
// CausalSelfAttention: x@Wqkv+b -> heads -> causal flash attn -> @Wproj+b
// B=2 T=2048 C=1024 H=16 Dh=64.
// R14: attn uniform-wave rebalance + full K/V depth-2 prefetch.
//  - R13 post-mortem: LPT backfill decayed (8.4% occupancy time-avg; light
//    blocks retire early, nothing refills). Balance must be per-wave uniform.
//  - Block = (u-pair, bh), grid 1024 x 128thr. Each wave runs q-group 63-u
//    THEN u (accO reused between groups -> no VGPR doubling). Parity split
//    gives EVERY wave 16-17 tiles; 2048 waves = 2/SIMD resident start->end.
//  - V prefetched depth-2 like K (vA/vB ping-pong, static indices): K+V for
//    kt+2 issued at tile top, consumed a full tile later -> L2 latency covered.
//  - __launch_bounds__(128,2): VGPR cap 256 (measured need ~180, no spill).
//  - l-sum via ones-column MFMA; P pack via v_cvt_pk_bf16_f32 (R13, kept).
// R12 (kept): gemm_qkv 256x192 3-phase pipelined, 256-block full coverage,
//  LDS XOR-swizzle (bank conflicts 3.1M->0), counted vmcnt(5), setprio.
// HARD-WON NOTES:
//  - R7: __launch_bounds__(256,4) forced VGPR=64 -> 380MB scratch spills.
//  - R8: V-frag loads after softmax doubled per-tile exposed latency.
//  - R13: VGPR 144 crossed the 128 cliff (3 waves/SIMD); occupancy-decay
//    from non-uniform block lengths dominates any per-tile op thinning.
// ---------------------------------------------------------------------------

using u16 = unsigned short;
using u32 = unsigned int;

typedef __bf16 bf16x8 __attribute__((ext_vector_type(8)));
typedef float f32x4 __attribute__((ext_vector_type(4)));

#define AS1 __attribute__((address_space(1)))
#define AS3 __attribute__((address_space(3)))

__device__ __forceinline__ u16 f2bf(float f) {
  u32 u = __float_as_uint(f);
  u += 0x7fffu + ((u >> 16) & 1u);   // RTNE
  return (u16)(u >> 16);
}
__device__ __forceinline__ u32 cvtpk(float a, float b) {
  u32 r;
  asm("v_cvt_pk_bf16_f32 %0, %1, %2" : "=v"(r) : "v"(a), "v"(b));
  return r;
}

// ---------------- prep: cvt x->bf16 (blocks 0..4095) + W transposes ---------
__global__ __launch_bounds__(256) void prep(const float* __restrict__ x,
                                            u16* __restrict__ xb,
                                            const float* __restrict__ W0,
                                            u16* __restrict__ T0,
                                            const float* __restrict__ W1,
                                            u16* __restrict__ T1) {
  const int bx = blockIdx.x;
  const int tid = threadIdx.x;
  if (bx < 4096) {
    const int i = bx * 256 + tid;
    float4 v = ((const float4*)x)[i];
    ushort4 o;
    o.x = f2bf(v.x); o.y = f2bf(v.y); o.z = f2bf(v.z); o.w = f2bf(v.w);
    ((ushort4*)xb)[i] = o;
    return;
  }
  __shared__ float t[32][33];
  const int idx = bx - 4096;          // 128 n-tiles x 32 k-tiles
  const int bxx = idx & 127, by = idx >> 7;
  const float* W; u16* Wt; int N, n0;
  if (bxx < 96) { W = W0; Wt = T0; N = 3072; n0 = bxx * 32; }
  else          { W = W1; Wt = T1; N = 1024; n0 = (bxx - 96) * 32; }
  const int k0 = by * 32;
  const int tx = tid & 31, ty = tid >> 5;
#pragma unroll
  for (int i = 0; i < 4; ++i)
    t[ty + i * 8][tx] = W[(size_t)(k0 + ty + i * 8) * N + n0 + tx];
  __syncthreads();
#pragma unroll
  for (int i = 0; i < 4; ++i)
    Wt[(size_t)(n0 + ty + i * 8) * 1024 + k0 + tx] = f2bf(t[tx][ty + i * 8]);
}

// ---------------- QKV GEMM: 256x192 3-phase pipelined -----------------------
// n<1024: Q (scaled by cs) -> qb[4096][1024]
// 1024<=n<2048: K -> KF fragment order [bh][kt][m][hh][lane][8]
// n>=2048:     V -> VF fragment order [bh][kt][hh][di][lane][8] (k-permuted)
#define MFMA16 __builtin_amdgcn_mfma_f32_16x16x32_bf16

__global__ __launch_bounds__(512, 2) void gemm_qkv(const u16* __restrict__ A,
                                                   const u16* __restrict__ Bt,
                                                   const float* __restrict__ bias,
                                                   u16* __restrict__ qb,
                                                   u16* __restrict__ KF,
                                                   u16* __restrict__ VF,
                                                   float sc_val) {
  constexpr int NT = 16;                    // K=1024 / BK=64
  constexpr int BUFO = 7 * 4096;            // u16 per buffer (7 chunks)
  __shared__ __align__(16) u16 sm[2 * BUFO];  // 112 KiB

  const int tid  = threadIdx.x;
  const int lane = tid & 63;
  const int w    = tid >> 6;          // 0..7
  const int quad = lane >> 4;
  const int l15  = lane & 15;

  // block -> tile: XCD-bijective (256 blocks = 8 XCD x 32), 4x8 region/XCD
  const int bid = blockIdx.x;
  const int xcd = bid & 7, c = bid >> 3;         // c 0..31
  const int mt = (xcd >> 1) * 4 + (c & 3);       // 0..15
  const int nt = (xcd & 1) * 8 + (c >> 2);       // 0..15
  const int bm = mt * 256, bn = nt * 192;

  const int wr = (w >> 2) * 128;      // wave rows (0/128)
  const int wc = (w & 3) * 48;        // wave cols (0/48/96/144)

  // ---- staging: thread writes 16B linearly at chunk + tid*16.
  // LDS row = tid>>3, granule = tid&7; source granule = (tid&7)^(row&7).
  const int srow = tid >> 3;
  const int scol = (((tid & 7) ^ ((tid >> 3) & 7)) << 3);

#define STAGEA(ch, ktile, bufo)                                                 \
  __builtin_amdgcn_global_load_lds(                                             \
      (AS1 const void*)(A + (size_t)(bm + (ch) * 64 + srow) * 1024 +            \
                        ((ktile) << 6) + scol),                                 \
      (AS3 void*)(sm + (bufo) + (ch) * 4096 + tid * 8), 16, 0, 0)
#define STAGEB(ch, ktile, bufo)                                                 \
  __builtin_amdgcn_global_load_lds(                                             \
      (AS1 const void*)(Bt + (size_t)(bn + (ch) * 64 + srow) * 1024 +           \
                        ((ktile) << 6) + scol),                                 \
      (AS3 void*)(sm + (bufo) + (4 + (ch)) * 4096 + tid * 8), 16, 0, 0)

  // ---- ds-read bases (swizzled granule; row&7 == l15&7 everywhere)
  const int ca = (w >> 2) * 2;        // A chunk base: 0 or 2
  int abase_lo[4], abase_hi[4], bbase[3];
#pragma unroll
  for (int mi = 0; mi < 4; ++mi) {
    abase_lo[mi] = (ca + 0) * 4096 + (mi * 16 + l15) * 64;
    abase_hi[mi] = (ca + 1) * 4096 + (mi * 16 + l15) * 64;
  }
#pragma unroll
  for (int ni = 0; ni < 3; ++ni) {
    const int rb = wc + ni * 16 + l15;            // 0..191
    bbase[ni] = (4 + (rb >> 6)) * 4096 + (rb & 63) * 64;
  }
  const int sw0 = ((quad ^ (l15 & 7)) << 3);
  const int sw1 = sw0 ^ 32;

  // ---- prologue: kt0 all 7 -> buf0; kt1 B0B1,B2A0A1 -> buf1
  STAGEA(0, 0, 0); STAGEA(1, 0, 0); STAGEA(2, 0, 0); STAGEA(3, 0, 0);
  STAGEB(0, 0, 0); STAGEB(1, 0, 0); STAGEB(2, 0, 0);
  STAGEB(0, 1, BUFO); STAGEB(1, 1, BUFO);
  STAGEB(2, 1, BUFO); STAGEA(0, 1, BUFO); STAGEA(1, 1, BUFO);
  asm volatile("s_waitcnt vmcnt(5)" ::: "memory");  // kt0 landed; kt1's 5 fly
  __builtin_amdgcn_s_barrier();

  f32x4 acc[8][3] = {};
  bf16x8 alo[4][2], ahi[4][2], b[3][2];

#pragma unroll 2
  for (int j = 0; j < NT; ++j) {
    const int bo  = (j & 1) * BUFO;
    const int nbo = bo ^ BUFO;
    const u16* smb = sm + bo;

    // ---------- phase 0: ds a_lo + b0,b1; stage A2A3(j+1); MFMA mi0-3 x ni0,1
#pragma unroll
    for (int mi = 0; mi < 4; ++mi) {
      alo[mi][0] = *(const bf16x8*)(smb + abase_lo[mi] + sw0);
      alo[mi][1] = *(const bf16x8*)(smb + abase_lo[mi] + sw1);
    }
#pragma unroll
    for (int ni = 0; ni < 2; ++ni) {
      b[ni][0] = *(const bf16x8*)(smb + bbase[ni] + sw0);
      b[ni][1] = *(const bf16x8*)(smb + bbase[ni] + sw1);
    }
    if (j + 1 < NT) { STAGEA(2, j + 1, nbo); STAGEA(3, j + 1, nbo); }
    __builtin_amdgcn_s_barrier();
    asm volatile("s_waitcnt lgkmcnt(0)" ::: "memory");
    __builtin_amdgcn_s_setprio(1);
#pragma unroll
    for (int mi = 0; mi < 4; ++mi)
#pragma unroll
      for (int ni = 0; ni < 2; ++ni) {
        acc[mi][ni] = MFMA16(alo[mi][0], b[ni][0], acc[mi][ni], 0, 0, 0);
        acc[mi][ni] = MFMA16(alo[mi][1], b[ni][1], acc[mi][ni], 0, 0, 0);
      }
    __builtin_amdgcn_s_setprio(0);
    __builtin_amdgcn_s_barrier();

    // ---------- phase 1: ds a_hi + b2; stage B0B1(j+2); MFMA mi0-3xni2 + mi4-7xni0
#pragma unroll
    for (int mi = 0; mi < 4; ++mi) {
      ahi[mi][0] = *(const bf16x8*)(smb + abase_hi[mi] + sw0);
      ahi[mi][1] = *(const bf16x8*)(smb + abase_hi[mi] + sw1);
    }
    b[2][0] = *(const bf16x8*)(smb + bbase[2] + sw0);
    b[2][1] = *(const bf16x8*)(smb + bbase[2] + sw1);
    if (j + 2 < NT) { STAGEB(0, j + 2, bo); STAGEB(1, j + 2, bo); }
    __builtin_amdgcn_s_barrier();
    asm volatile("s_waitcnt lgkmcnt(0)" ::: "memory");
    __builtin_amdgcn_s_setprio(1);
#pragma unroll
    for (int mi = 0; mi < 4; ++mi) {
      acc[mi][2] = MFMA16(alo[mi][0], b[2][0], acc[mi][2], 0, 0, 0);
      acc[mi][2] = MFMA16(alo[mi][1], b[2][1], acc[mi][2], 0, 0, 0);
      acc[4 + mi][0] = MFMA16(ahi[mi][0], b[0][0], acc[4 + mi][0], 0, 0, 0);
      acc[4 + mi][0] = MFMA16(ahi[mi][1], b[0][1], acc[4 + mi][0], 0, 0, 0);
    }
    __builtin_amdgcn_s_setprio(0);
    __builtin_amdgcn_s_barrier();

    // ---------- phase 2: stage B2,A0,A1(j+2); MFMA mi4-7 x ni1,2; vmcnt(5)
    if (j + 2 < NT) { STAGEB(2, j + 2, bo); STAGEA(0, j + 2, bo); STAGEA(1, j + 2, bo); }
    __builtin_amdgcn_s_barrier();
    __builtin_amdgcn_s_setprio(1);
#pragma unroll
    for (int mi = 0; mi < 4; ++mi)
#pragma unroll
      for (int ni = 1; ni < 3; ++ni) {
        acc[4 + mi][ni] = MFMA16(ahi[mi][0], b[ni][0], acc[4 + mi][ni], 0, 0, 0);
        acc[4 + mi][ni] = MFMA16(ahi[mi][1], b[ni][1], acc[4 + mi][ni], 0, 0, 0);
      }
    __builtin_amdgcn_s_setprio(0);
    if (j + 2 < NT)
      asm volatile("s_waitcnt vmcnt(5)" ::: "memory"); // drains A2A3(j+1)+older
    else
      asm volatile("s_waitcnt vmcnt(0)" ::: "memory"); // tail drain
    __builtin_amdgcn_s_barrier();
  }
#undef STAGEA
#undef STAGEB

  // ---- epilogue: per-ni region branch (192-wide blocks straddle Q/K/V) ----
  const int crow0 = bm + wr + (quad << 2);
  const int ccol0 = bn + wc + l15;
#pragma unroll
  for (int ni = 0; ni < 3; ++ni) {
    const int n = ccol0 + ni * 16;
    const float bv = bias[n];
    if (n < 1024) {                     // ---- Q (scaled) ----
#pragma unroll
      for (int mi = 0; mi < 8; ++mi) {
        const int m0 = crow0 + mi * 16;
#pragma unroll
        for (int r = 0; r < 4; ++r)
          qb[(size_t)(m0 + r) * 1024 + n] = f2bf((acc[mi][ni][r] + bv) * sc_val);
      }
    } else if (n < 2048) {              // ---- K fragment order ----
      const int hk = (n - 1024) >> 6;
      const int d  = (n - 1024) & 63;
      const int hh = d >> 5, qd = (d >> 3) & 3, jj = d & 7;
#pragma unroll
      for (int mi = 0; mi < 8; ++mi) {
#pragma unroll
        for (int r = 0; r < 4; ++r) {
          const int t  = crow0 + mi * 16 + r;
          const int bb = t >> 11, tt = t & 2047;
          const int kt = tt >> 6, mm = (tt >> 4) & 3, l = tt & 15;
          KF[((size_t)((bb * 16 + hk) * 32 + kt) * 8 + mm * 2 + hh) * 512 +
             (qd * 16 + l) * 8 + jj] = f2bf(acc[mi][ni][r] + bv);
        }
      }
    } else {                            // ---- V fragment order (k-perm) ----
      const int hv = (n - 2048) >> 6;
      const int d  = (n - 2048) & 63;
      const int di = d >> 4, l = d & 15;
#pragma unroll
      for (int mi = 0; mi < 8; ++mi) {
#pragma unroll
        for (int r = 0; r < 4; ++r) {
          const int t  = crow0 + mi * 16 + r;
          const int bb = t >> 11, tt = t & 2047;
          const int kt = tt >> 6, to = tt & 63;
          const int mq = to >> 4, qd2 = (to >> 2) & 3, rr = to & 3;
          const int hh = mq >> 1, jj = (mq & 1) * 4 + rr;
          VF[((size_t)((bb * 16 + hv) * 32 + kt) * 8 + hh * 4 + di) * 512 +
             (qd2 * 16 + l) * 8 + jj] = f2bf(acc[mi][ni][r] + bv);
        }
      }
    }
  }
}

// ---------------- Proj GEMM: 128x64 tile, fp32 out --------------------------
__global__ __launch_bounds__(256) void gemm_proj(const u16* __restrict__ A,
                                                 const u16* __restrict__ Bt,
                                                 const float* __restrict__ bias,
                                                 float* __restrict__ C) {
  constexpr int BM = 128, BN = 64, BK = 32;
  constexpr int K = 1024, N = 1024;
  __shared__ __align__(16) u16 lA[BM * BK];
  __shared__ __align__(16) u16 lB[BN * BK];
  const int tid  = threadIdx.x;
  const int lane = tid & 63;
  const int wave = tid >> 6;
  const int bm = blockIdx.x * BM;
  const int bn = blockIdx.y * BN;
  const int wr = wave * 32;

  f32x4 acc[2][4] = {};

  const int f0 = (wave << 10) + (lane << 4);
  const int f1 = f0 + 4096;
  const int ar0 = f0 >> 6, ac0 = (f0 & 63) >> 1;
  const int ar1 = f1 >> 6, ac1 = (f1 & 63) >> 1;

  const int arow = wr + (lane & 15);
  const int brow = (lane & 15);
  const int kk   = (lane >> 4) << 3;

  for (int k0 = 0; k0 < K; k0 += BK) {
    __builtin_amdgcn_global_load_lds((AS1 const void*)(A + (size_t)(bm + ar0) * K + k0 + ac0),
                                     (AS3 void*)(lA + (wave << 9)), 16, 0, 0);
    __builtin_amdgcn_global_load_lds((AS1 const void*)(A + (size_t)(bm + ar1) * K + k0 + ac1),
                                     (AS3 void*)(lA + ((wave + 4) << 9)), 16, 0, 0);
    __builtin_amdgcn_global_load_lds((AS1 const void*)(Bt + (size_t)(bn + ar0) * K + k0 + ac0),
                                     (AS3 void*)(lB + (wave << 9)), 16, 0, 0);
    __syncthreads();

    bf16x8 af[2], bfr[4];
#pragma unroll
    for (int mi = 0; mi < 2; ++mi)
      af[mi] = *(const bf16x8*)&lA[(arow + mi * 16) * BK + kk];
#pragma unroll
    for (int ni = 0; ni < 4; ++ni)
      bfr[ni] = *(const bf16x8*)&lB[(brow + ni * 16) * BK + kk];
#pragma unroll
    for (int mi = 0; mi < 2; ++mi)
#pragma unroll
      for (int ni = 0; ni < 4; ++ni)
        acc[mi][ni] = __builtin_amdgcn_mfma_f32_16x16x32_bf16(af[mi], bfr[ni],
                                                              acc[mi][ni], 0, 0, 0);
    __syncthreads();
  }

  const int crow0 = bm + wr + ((lane >> 4) << 2);
  const int ccol0 = bn + (lane & 15);
#pragma unroll
  for (int ni = 0; ni < 4; ++ni) {
    const int n = ccol0 + ni * 16;
    const float bv = bias[n];
#pragma unroll
    for (int mi = 0; mi < 2; ++mi) {
      const int m0 = crow0 + mi * 16;
#pragma unroll
      for (int r = 0; r < 4; ++r)
        C[(size_t)(m0 + r) * N + n] = acc[mi][ni][r] + bv;
    }
  }
}

// ---------------- uniform-wave pipelined MFMA flash attention ---------------
// grid 1024 x 128 threads.  bid: xcd = bid&7 (4 bh per XCD, KV L2-resident);
// c = bid>>3: u = c&31 (q-group pair), bh = xcd | ((c>>5)<<3).
// Each wave: q-group 63-u fully, then q-group u (accO reused between groups).
// Parity waves split kt; per-wave total = 16-17 tiles UNIFORMLY across the
// whole grid -> 2 waves/SIMD resident for the entire kernel, no decay.
// K AND V prefetched depth-2 (kA/kB, vA/vB static ping-pong).
__global__ __launch_bounds__(128, 2) void attn_bal(const u16* __restrict__ qb,
                                                   const u16* __restrict__ KF,
                                                   const u16* __restrict__ VF,
                                                   u16* __restrict__ out) {
  const int bid = blockIdx.x;
  const int c   = bid >> 3;
  const int u   = c & 31;
  const int bh  = (bid & 7) | ((c >> 5) << 3);
  const int b = bh >> 4, h = bh & 15;
  const int tid = threadIdx.x;
  const int lane = tid & 63;
  const int par  = tid >> 6;          // wave 0/1 = kt parity
  const int quad = lane >> 4;
  const int l15  = lane & 15;

  __shared__ float CB[64][41];        // [lane][32 accO + 8 accL], stride 41

  const u16* qbase = qb + (size_t)b * 2048 * 1024 + h * 64;
  const size_t fb = (size_t)bh * 32 * 4096 + lane * 8;
  const u16* kfb = KF + fb;
  const u16* vfb = VF + fb;

  union { u32 u4[4]; bf16x8 v; } onesu;
  onesu.u4[0] = onesu.u4[1] = onesu.u4[2] = onesu.u4[3] = 0x3f803f80u;
  const bf16x8 onesf = onesu.v;       // bf16 1.0 x8

  u16* const outb = out + (size_t)b * 2048 * 1024 + h * 64 + l15;

  auto run_group = [&](int g32) {
    const int q0 = g32 * 32;
    const int ktmax = g32 >> 1;

    // Q B-frags for this group
    bf16x8 qf[2][2];
#pragma unroll
    for (int g = 0; g < 2; ++g)
#pragma unroll
      for (int hh = 0; hh < 2; ++hh)
        qf[g][hh] = *(const bf16x8*)(qbase + (size_t)(q0 + g * 16 + l15) * 1024 +
                                     hh * 32 + quad * 8);

    f32x4 accO[2][4] = {};            // [g][di]: q=quad*4+r, d=di*16+l15
    f32x4 accL[2] = {};               // [g]: l for q=quad*4+r

    // depth-2 K+V pipeline, two register sets (static ping-pong, no rotate)
    bf16x8 kA[4][2], kB[4][2], vA[2][4], vB[2][4];
    {
      const u16* kp = kfb + (size_t)par * 4096;
      const u16* vp = vfb + (size_t)par * 4096;
#pragma unroll
      for (int m = 0; m < 4; ++m)
#pragma unroll
        for (int hh = 0; hh < 2; ++hh)
          kA[m][hh] = *(const bf16x8*)(kp + (m * 2 + hh) * 512);
#pragma unroll
      for (int hh = 0; hh < 2; ++hh)
#pragma unroll
        for (int di = 0; di < 4; ++di)
          vA[hh][di] = *(const bf16x8*)(vp + (hh * 4 + di) * 512);
    }

    auto tile = [&](int kt, bf16x8 (&KC)[4][2], bf16x8 (&KN)[4][2],
                    bf16x8 (&VC)[2][4], bf16x8 (&VN)[2][4]) {
      // prefetch kt+2 (clamped) into the other register set
      const int ktn = (kt + 2 <= ktmax) ? kt + 2 : ktmax;
      const u16* kpn = kfb + (size_t)ktn * 4096;
      const u16* vpn = vfb + (size_t)ktn * 4096;
#pragma unroll
      for (int m = 0; m < 4; ++m)
#pragma unroll
        for (int hh = 0; hh < 2; ++hh)
          KN[m][hh] = *(const bf16x8*)(kpn + (m * 2 + hh) * 512);
#pragma unroll
      for (int hh = 0; hh < 2; ++hh)
#pragma unroll
        for (int di = 0; di < 4; ++di)
          VN[hh][di] = *(const bf16x8*)(vpn + (hh * 4 + di) * 512);

      const bool diag = (kt == ktmax);
      bf16x8 ap[2][2];
#pragma unroll
      for (int g = 0; g < 2; ++g) {
        f32x4 sT[4] = {};
#pragma unroll
        for (int m = 0; m < 4; ++m) {
          sT[m] = MFMA16(KC[m][0], qf[g][0], sT[m], 0, 0, 0);
          sT[m] = MFMA16(KC[m][1], qf[g][1], sT[m], 0, 0, 0);
        }
        float pv[4][4];
        if (diag) {                    // only the last tile pays mask ops
          const int qgl = q0 + g * 16 + l15;
#pragma unroll
          for (int m = 0; m < 4; ++m)
#pragma unroll
            for (int r = 0; r < 4; ++r) {
              const bool msk = (kt * 64 + m * 16 + quad * 4 + r) > qgl;
              pv[m][r] = msk ? 0.f : __builtin_amdgcn_exp2f(sT[m][r]);
            }
        } else {
#pragma unroll
          for (int m = 0; m < 4; ++m)
#pragma unroll
            for (int r = 0; r < 4; ++r)
              pv[m][r] = __builtin_amdgcn_exp2f(sT[m][r]);
        }
        union { u32 u4[4]; bf16x8 v; } t0, t1;
        t0.u4[0] = cvtpk(pv[0][0], pv[0][1]);
        t0.u4[1] = cvtpk(pv[0][2], pv[0][3]);
        t0.u4[2] = cvtpk(pv[1][0], pv[1][1]);
        t0.u4[3] = cvtpk(pv[1][2], pv[1][3]);
        t1.u4[0] = cvtpk(pv[2][0], pv[2][1]);
        t1.u4[1] = cvtpk(pv[2][2], pv[2][3]);
        t1.u4[2] = cvtpk(pv[3][0], pv[3][1]);
        t1.u4[3] = cvtpk(pv[3][2], pv[3][3]);
        ap[g][0] = t0.v;
        ap[g][1] = t1.v;
      }

      // O += P.V
#pragma unroll
      for (int hh = 0; hh < 2; ++hh)
#pragma unroll
        for (int di = 0; di < 4; ++di) {
          bf16x8 bv = VC[hh][di];
#pragma unroll
          for (int g = 0; g < 2; ++g)
            accO[g][di] = MFMA16(ap[g][hh], bv, accO[g][di], 0, 0, 0);
        }
      // l += P.1 (MFMA does the cross-quad k-reduction)
#pragma unroll
      for (int g = 0; g < 2; ++g) {
        accL[g] = MFMA16(ap[g][0], onesf, accL[g], 0, 0, 0);
        accL[g] = MFMA16(ap[g][1], onesf, accL[g], 0, 0, 0);
      }
    };

    for (int kt = par; kt <= ktmax; ) {
      tile(kt, kA, kB, vA, vB); kt += 2;
      if (kt > ktmax) break;
      tile(kt, kB, kA, vB, vA); kt += 2;
    }

    // ---- exact parity combine (per-lane values) ----
    if (par) {
      float* cb = CB[lane];
#pragma unroll
      for (int g = 0; g < 2; ++g) {
#pragma unroll
        for (int di = 0; di < 4; ++di)
#pragma unroll
          for (int r = 0; r < 4; ++r)
            cb[g * 16 + di * 4 + r] = accO[g][di][r];
#pragma unroll
        for (int r = 0; r < 4; ++r)
          cb[32 + g * 4 + r] = accL[g][r];
      }
    }
    __syncthreads();
    if (!par) {
      const float* cb = CB[lane];
#pragma unroll
      for (int g = 0; g < 2; ++g) {
#pragma unroll
        for (int di = 0; di < 4; ++di)
#pragma unroll
          for (int r = 0; r < 4; ++r)
            accO[g][di][r] += cb[g * 16 + di * 4 + r];
#pragma unroll
        for (int r = 0; r < 4; ++r)
          accL[g][r] += cb[32 + g * 4 + r];
      }
#pragma unroll
      for (int g = 0; g < 2; ++g)
#pragma unroll
        for (int r = 0; r < 4; ++r) {
          const float inv = 1.f / accL[g][r]; // lane holds l for its own rows
          const int q = q0 + g * 16 + quad * 4 + r;
          u16* op = outb + (size_t)q * 1024;
#pragma unroll
          for (int di = 0; di < 4; ++di)
            op[di * 16] = f2bf(accO[g][di][r] * inv);
        }
    }
    __syncthreads();   // CB safe for reuse by the next group
  };

  run_group(63 - u);   // heavy half
  run_group(u);        // light half -> every wave totals 16-17 tiles
}

// ---------------------------------------------------------------------------
extern "C" void kernel_launch(void* const* d_in, const int* in_sizes, int n_in,
                              void* d_out, int out_size, void* d_ws, size_t ws_size,
                              hipStream_t stream) {
  const float* x     = (const float*)d_in[0];
  const float* Wqkv  = (const float*)d_in[1];
  const float* bqkv  = (const float*)d_in[2];
  const float* Wproj = (const float*)d_in[3];
  const float* bproj = (const float*)d_in[4];
  float* out = (float*)d_out;

  char* ws = (char*)d_ws;
  u16* xb     = (u16*)(ws);                 //  8 MB  x bf16 [4096,1024]
  u16* wqkvT  = (u16*)(ws + 8388608);       //  6 MB  Wqkv^T bf16 [3072,1024]
  u16* wprojT = (u16*)(ws + 14680064);      //  2 MB  Wproj^T bf16 [1024,1024]
  u16* qb     = (u16*)(ws + 16777216);      //  8 MB  Q bf16 [4096,1024] (pre-scaled)
  u16* KF     = (u16*)(ws + 25165824);      //  8 MB  K fragment-order
  u16* VF     = (u16*)(ws + 33554432);      //  8 MB  V fragment-order (k-perm)
  u16* att    = (u16*)(ws + 41943040);      //  8 MB  attn out bf16 [4096,1024]

  constexpr float cs = 0.18033688011f;      // log2(e)/8

  prep<<<8192, 256, 0, stream>>>(x, xb, Wqkv, wqkvT, Wproj, wprojT);

  gemm_qkv<<<dim3(256), 512, 0, stream>>>(xb, wqkvT, bqkv, qb, KF, VF, cs);

  attn_bal<<<dim3(1024), 128, 0, stream>>>(qb, KF, VF, att);

  gemm_proj<<<dim3(32, 16), 256, 0, stream>>>(att, wprojT, bproj, out);
}

// Round 5
// 156.177 us; speedup vs baseline: 1.0775x; 1.0198x over previous
//
#include <hip/hip_runtime.h>
#include <hip/hip_bf16.h>
#include <cstdint>

// ---------------------------------------------------------------------------
// CausalSelfAttention: x@Wqkv+b -> heads -> causal flash attn -> @Wproj+b
// B=2 T=2048 C=1024 H=16 Dh=64.
// R15: gemm_proj ported to the pipelined template (was the worst kernel at
//  ~29us / ~296 TF with the old BK=32 2-phase-drain structure).
//  - BM=128 BN=128 BK=64, 256thr (4 waves @ 64x64, acc[4][4]).
//  - grid 256 blocks (32x8), XCD-mapped: xcd owns 4 mt x all nt.
//  - LDS 64KB: 2 bufs x 4 chunks [64][64] u16 (A0,A1,B0,B1) -> 2 blocks/CU.
//  - 2 phases/K-tile: p0 {ds a+b01 | stage B(j+1)->other | 16 MFMA},
//    p1 {ds b23 | stage A(j+2)->cur | 16 MFMA; vmcnt(4)}.
//    Hazards: A chunks drained at p0 barrier (A(j+2) staged p1); B drained at
//    p1 barrier (B(j+1) staged p0 of next... i.e. into buffer whose B was
//    read last iteration). vmcnt(4) leaves exactly A(j+2) in flight.
//  - Granule XOR-swizzle, inverse-swizzle pre-applied to global source.
// R14 (kept): attn uniform-wave (run 63-u then u per wave), K+V depth-2
//  ping-pong, l via ones-MFMA, cvt_pk pack. R12 (kept): gemm_qkv 256x192
//  3-phase, counted vmcnt(5), swizzle (conflicts 3.1M->0), full coverage.
// HARD-WON NOTES:
//  - R7: forcing low VGPR (launch_bounds 256,4) -> catastrophic spills.
//  - R8: V-frag loads after softmax doubled per-tile exposed latency.
//  - R13: VGPR 144 crossed the 128 cliff; occupancy-DECAY from non-uniform
//    block lengths dominates per-tile op thinning. Balance per-wave.
//  - R11: 256^2 tile -> 192 blocks left 64 CUs idle; full coverage first.
// ---------------------------------------------------------------------------

using u16 = unsigned short;
using u32 = unsigned int;

typedef __bf16 bf16x8 __attribute__((ext_vector_type(8)));
typedef float f32x4 __attribute__((ext_vector_type(4)));

#define AS1 __attribute__((address_space(1)))
#define AS3 __attribute__((address_space(3)))

__device__ __forceinline__ u16 f2bf(float f) {
  u32 u = __float_as_uint(f);
  u += 0x7fffu + ((u >> 16) & 1u);   // RTNE
  return (u16)(u >> 16);
}
__device__ __forceinline__ u32 cvtpk(float a, float b) {
  u32 r;
  asm("v_cvt_pk_bf16_f32 %0, %1, %2" : "=v"(r) : "v"(a), "v"(b));
  return r;
}

// ---------------- prep: cvt x->bf16 (blocks 0..4095) + W transposes ---------
__global__ __launch_bounds__(256) void prep(const float* __restrict__ x,
                                            u16* __restrict__ xb,
                                            const float* __restrict__ W0,
                                            u16* __restrict__ T0,
                                            const float* __restrict__ W1,
                                            u16* __restrict__ T1) {
  const int bx = blockIdx.x;
  const int tid = threadIdx.x;
  if (bx < 4096) {
    const int i = bx * 256 + tid;
    float4 v = ((const float4*)x)[i];
    ushort4 o;
    o.x = f2bf(v.x); o.y = f2bf(v.y); o.z = f2bf(v.z); o.w = f2bf(v.w);
    ((ushort4*)xb)[i] = o;
    return;
  }
  __shared__ float t[32][33];
  const int idx = bx - 4096;          // 128 n-tiles x 32 k-tiles
  const int bxx = idx & 127, by = idx >> 7;
  const float* W; u16* Wt; int N, n0;
  if (bxx < 96) { W = W0; Wt = T0; N = 3072; n0 = bxx * 32; }
  else          { W = W1; Wt = T1; N = 1024; n0 = (bxx - 96) * 32; }
  const int k0 = by * 32;
  const int tx = tid & 31, ty = tid >> 5;
#pragma unroll
  for (int i = 0; i < 4; ++i)
    t[ty + i * 8][tx] = W[(size_t)(k0 + ty + i * 8) * N + n0 + tx];
  __syncthreads();
#pragma unroll
  for (int i = 0; i < 4; ++i)
    Wt[(size_t)(n0 + ty + i * 8) * 1024 + k0 + tx] = f2bf(t[tx][ty + i * 8]);
}

// ---------------- QKV GEMM: 256x192 3-phase pipelined -----------------------
// n<1024: Q (scaled by cs) -> qb[4096][1024]
// 1024<=n<2048: K -> KF fragment order [bh][kt][m][hh][lane][8]
// n>=2048:     V -> VF fragment order [bh][kt][hh][di][lane][8] (k-permuted)
#define MFMA16 __builtin_amdgcn_mfma_f32_16x16x32_bf16

__global__ __launch_bounds__(512, 2) void gemm_qkv(const u16* __restrict__ A,
                                                   const u16* __restrict__ Bt,
                                                   const float* __restrict__ bias,
                                                   u16* __restrict__ qb,
                                                   u16* __restrict__ KF,
                                                   u16* __restrict__ VF,
                                                   float sc_val) {
  constexpr int NT = 16;                    // K=1024 / BK=64
  constexpr int BUFO = 7 * 4096;            // u16 per buffer (7 chunks)
  __shared__ __align__(16) u16 sm[2 * BUFO];  // 112 KiB

  const int tid  = threadIdx.x;
  const int lane = tid & 63;
  const int w    = tid >> 6;          // 0..7
  const int quad = lane >> 4;
  const int l15  = lane & 15;

  // block -> tile: XCD-bijective (256 blocks = 8 XCD x 32), 4x8 region/XCD
  const int bid = blockIdx.x;
  const int xcd = bid & 7, c = bid >> 3;         // c 0..31
  const int mt = (xcd >> 1) * 4 + (c & 3);       // 0..15
  const int nt = (xcd & 1) * 8 + (c >> 2);       // 0..15
  const int bm = mt * 256, bn = nt * 192;

  const int wr = (w >> 2) * 128;      // wave rows (0/128)
  const int wc = (w & 3) * 48;        // wave cols (0/48/96/144)

  // ---- staging: thread writes 16B linearly at chunk + tid*16.
  // LDS row = tid>>3, granule = tid&7; source granule = (tid&7)^(row&7).
  const int srow = tid >> 3;
  const int scol = (((tid & 7) ^ ((tid >> 3) & 7)) << 3);

#define STAGEA(ch, ktile, bufo)                                                 \
  __builtin_amdgcn_global_load_lds(                                             \
      (AS1 const void*)(A + (size_t)(bm + (ch) * 64 + srow) * 1024 +            \
                        ((ktile) << 6) + scol),                                 \
      (AS3 void*)(sm + (bufo) + (ch) * 4096 + tid * 8), 16, 0, 0)
#define STAGEB(ch, ktile, bufo)                                                 \
  __builtin_amdgcn_global_load_lds(                                             \
      (AS1 const void*)(Bt + (size_t)(bn + (ch) * 64 + srow) * 1024 +           \
                        ((ktile) << 6) + scol),                                 \
      (AS3 void*)(sm + (bufo) + (4 + (ch)) * 4096 + tid * 8), 16, 0, 0)

  // ---- ds-read bases (swizzled granule; row&7 == l15&7 everywhere)
  const int ca = (w >> 2) * 2;        // A chunk base: 0 or 2
  int abase_lo[4], abase_hi[4], bbase[3];
#pragma unroll
  for (int mi = 0; mi < 4; ++mi) {
    abase_lo[mi] = (ca + 0) * 4096 + (mi * 16 + l15) * 64;
    abase_hi[mi] = (ca + 1) * 4096 + (mi * 16 + l15) * 64;
  }
#pragma unroll
  for (int ni = 0; ni < 3; ++ni) {
    const int rb = wc + ni * 16 + l15;            // 0..191
    bbase[ni] = (4 + (rb >> 6)) * 4096 + (rb & 63) * 64;
  }
  const int sw0 = ((quad ^ (l15 & 7)) << 3);
  const int sw1 = sw0 ^ 32;

  // ---- prologue: kt0 all 7 -> buf0; kt1 B0B1,B2A0A1 -> buf1
  STAGEA(0, 0, 0); STAGEA(1, 0, 0); STAGEA(2, 0, 0); STAGEA(3, 0, 0);
  STAGEB(0, 0, 0); STAGEB(1, 0, 0); STAGEB(2, 0, 0);
  STAGEB(0, 1, BUFO); STAGEB(1, 1, BUFO);
  STAGEB(2, 1, BUFO); STAGEA(0, 1, BUFO); STAGEA(1, 1, BUFO);
  asm volatile("s_waitcnt vmcnt(5)" ::: "memory");  // kt0 landed; kt1's 5 fly
  __builtin_amdgcn_s_barrier();

  f32x4 acc[8][3] = {};
  bf16x8 alo[4][2], ahi[4][2], b[3][2];

#pragma unroll 2
  for (int j = 0; j < NT; ++j) {
    const int bo  = (j & 1) * BUFO;
    const int nbo = bo ^ BUFO;
    const u16* smb = sm + bo;

    // ---------- phase 0: ds a_lo + b0,b1; stage A2A3(j+1); MFMA mi0-3 x ni0,1
#pragma unroll
    for (int mi = 0; mi < 4; ++mi) {
      alo[mi][0] = *(const bf16x8*)(smb + abase_lo[mi] + sw0);
      alo[mi][1] = *(const bf16x8*)(smb + abase_lo[mi] + sw1);
    }
#pragma unroll
    for (int ni = 0; ni < 2; ++ni) {
      b[ni][0] = *(const bf16x8*)(smb + bbase[ni] + sw0);
      b[ni][1] = *(const bf16x8*)(smb + bbase[ni] + sw1);
    }
    if (j + 1 < NT) { STAGEA(2, j + 1, nbo); STAGEA(3, j + 1, nbo); }
    __builtin_amdgcn_s_barrier();
    asm volatile("s_waitcnt lgkmcnt(0)" ::: "memory");
    __builtin_amdgcn_s_setprio(1);
#pragma unroll
    for (int mi = 0; mi < 4; ++mi)
#pragma unroll
      for (int ni = 0; ni < 2; ++ni) {
        acc[mi][ni] = MFMA16(alo[mi][0], b[ni][0], acc[mi][ni], 0, 0, 0);
        acc[mi][ni] = MFMA16(alo[mi][1], b[ni][1], acc[mi][ni], 0, 0, 0);
      }
    __builtin_amdgcn_s_setprio(0);
    __builtin_amdgcn_s_barrier();

    // ---------- phase 1: ds a_hi + b2; stage B0B1(j+2); MFMA mi0-3xni2 + mi4-7xni0
#pragma unroll
    for (int mi = 0; mi < 4; ++mi) {
      ahi[mi][0] = *(const bf16x8*)(smb + abase_hi[mi] + sw0);
      ahi[mi][1] = *(const bf16x8*)(smb + abase_hi[mi] + sw1);
    }
    b[2][0] = *(const bf16x8*)(smb + bbase[2] + sw0);
    b[2][1] = *(const bf16x8*)(smb + bbase[2] + sw1);
    if (j + 2 < NT) { STAGEB(0, j + 2, bo); STAGEB(1, j + 2, bo); }
    __builtin_amdgcn_s_barrier();
    asm volatile("s_waitcnt lgkmcnt(0)" ::: "memory");
    __builtin_amdgcn_s_setprio(1);
#pragma unroll
    for (int mi = 0; mi < 4; ++mi) {
      acc[mi][2] = MFMA16(alo[mi][0], b[2][0], acc[mi][2], 0, 0, 0);
      acc[mi][2] = MFMA16(alo[mi][1], b[2][1], acc[mi][2], 0, 0, 0);
      acc[4 + mi][0] = MFMA16(ahi[mi][0], b[0][0], acc[4 + mi][0], 0, 0, 0);
      acc[4 + mi][0] = MFMA16(ahi[mi][1], b[0][1], acc[4 + mi][0], 0, 0, 0);
    }
    __builtin_amdgcn_s_setprio(0);
    __builtin_amdgcn_s_barrier();

    // ---------- phase 2: stage B2,A0,A1(j+2); MFMA mi4-7 x ni1,2; vmcnt(5)
    if (j + 2 < NT) { STAGEB(2, j + 2, bo); STAGEA(0, j + 2, bo); STAGEA(1, j + 2, bo); }
    __builtin_amdgcn_s_barrier();
    __builtin_amdgcn_s_setprio(1);
#pragma unroll
    for (int mi = 0; mi < 4; ++mi)
#pragma unroll
      for (int ni = 1; ni < 3; ++ni) {
        acc[4 + mi][ni] = MFMA16(ahi[mi][0], b[ni][0], acc[4 + mi][ni], 0, 0, 0);
        acc[4 + mi][ni] = MFMA16(ahi[mi][1], b[ni][1], acc[4 + mi][ni], 0, 0, 0);
      }
    __builtin_amdgcn_s_setprio(0);
    if (j + 2 < NT)
      asm volatile("s_waitcnt vmcnt(5)" ::: "memory"); // drains A2A3(j+1)+older
    else
      asm volatile("s_waitcnt vmcnt(0)" ::: "memory"); // tail drain
    __builtin_amdgcn_s_barrier();
  }
#undef STAGEA
#undef STAGEB

  // ---- epilogue: per-ni region branch (192-wide blocks straddle Q/K/V) ----
  const int crow0 = bm + wr + (quad << 2);
  const int ccol0 = bn + wc + l15;
#pragma unroll
  for (int ni = 0; ni < 3; ++ni) {
    const int n = ccol0 + ni * 16;
    const float bv = bias[n];
    if (n < 1024) {                     // ---- Q (scaled) ----
#pragma unroll
      for (int mi = 0; mi < 8; ++mi) {
        const int m0 = crow0 + mi * 16;
#pragma unroll
        for (int r = 0; r < 4; ++r)
          qb[(size_t)(m0 + r) * 1024 + n] = f2bf((acc[mi][ni][r] + bv) * sc_val);
      }
    } else if (n < 2048) {              // ---- K fragment order ----
      const int hk = (n - 1024) >> 6;
      const int d  = (n - 1024) & 63;
      const int hh = d >> 5, qd = (d >> 3) & 3, jj = d & 7;
#pragma unroll
      for (int mi = 0; mi < 8; ++mi) {
#pragma unroll
        for (int r = 0; r < 4; ++r) {
          const int t  = crow0 + mi * 16 + r;
          const int bb = t >> 11, tt = t & 2047;
          const int kt = tt >> 6, mm = (tt >> 4) & 3, l = tt & 15;
          KF[((size_t)((bb * 16 + hk) * 32 + kt) * 8 + mm * 2 + hh) * 512 +
             (qd * 16 + l) * 8 + jj] = f2bf(acc[mi][ni][r] + bv);
        }
      }
    } else {                            // ---- V fragment order (k-perm) ----
      const int hv = (n - 2048) >> 6;
      const int d  = (n - 2048) & 63;
      const int di = d >> 4, l = d & 15;
#pragma unroll
      for (int mi = 0; mi < 8; ++mi) {
#pragma unroll
        for (int r = 0; r < 4; ++r) {
          const int t  = crow0 + mi * 16 + r;
          const int bb = t >> 11, tt = t & 2047;
          const int kt = tt >> 6, to = tt & 63;
          const int mq = to >> 4, qd2 = (to >> 2) & 3, rr = to & 3;
          const int hh = mq >> 1, jj = (mq & 1) * 4 + rr;
          VF[((size_t)((bb * 16 + hv) * 32 + kt) * 8 + hh * 4 + di) * 512 +
             (qd2 * 16 + l) * 8 + jj] = f2bf(acc[mi][ni][r] + bv);
        }
      }
    }
  }
}

// ---------------- Proj GEMM: 128x128, BK=64, pipelined (R15) ----------------
// M=4096 N=1024 K=1024, fp32 out.  256 blocks (32 mt x 8 nt), 256 thr.
// 4 waves @ 64x64 (acc[4][4]).  LDS 2 bufs x {A0,A1,B0,B1} [64][64] = 64 KiB.
__global__ __launch_bounds__(256, 2) void gemm_proj(const u16* __restrict__ A,
                                                    const u16* __restrict__ Bt,
                                                    const float* __restrict__ bias,
                                                    float* __restrict__ C) {
  constexpr int NT = 16;                    // K=1024 / BK=64
  constexpr int BUFO = 4 * 4096;            // u16 per buffer (4 chunks)
  __shared__ __align__(16) u16 sm[2 * BUFO];  // 64 KiB

  const int tid  = threadIdx.x;
  const int lane = tid & 63;
  const int w    = tid >> 6;          // 0..3
  const int quad = lane >> 4;
  const int l15  = lane & 15;

  // 256 blocks = 8 XCD x 32: each XCD owns 4 consecutive mt x all 8 nt
  const int bid = blockIdx.x;
  const int xcd = bid & 7, c = bid >> 3;     // c 0..31
  const int mt = xcd * 4 + (c & 3);          // 0..31
  const int nt = c >> 2;                     // 0..7
  const int bm = mt * 128, bn = nt * 128;

  const int wr = (w >> 1) * 64;       // wave rows (0/64)
  const int wcC = (w & 1) * 64;       // wave cols (0/64)

  // staging: thread covers row tid>>3 (and +32), granule tid&7 (swizzled src)
  const int srow = tid >> 3;
  const int scol = (((tid & 7) ^ ((tid >> 3) & 7)) << 3);

#define PSTAGEA(ch, ktile, bufo)                                                \
  do {                                                                          \
    const u16* _s = A + (size_t)(bm + (ch) * 64 + srow) * 1024 +                \
                    ((ktile) << 6) + scol;                                      \
    u16* _d = sm + (bufo) + (ch) * 4096 + tid * 8;                              \
    __builtin_amdgcn_global_load_lds((AS1 const void*)_s, (AS3 void*)_d,        \
                                     16, 0, 0);                                 \
    __builtin_amdgcn_global_load_lds((AS1 const void*)(_s + (32 << 10)),        \
                                     (AS3 void*)(_d + 2048), 16, 0, 0);         \
  } while (0)
#define PSTAGEB(ch, ktile, bufo)                                                \
  do {                                                                          \
    const u16* _s = Bt + (size_t)(bn + (ch) * 64 + srow) * 1024 +               \
                    ((ktile) << 6) + scol;                                      \
    u16* _d = sm + (bufo) + (2 + (ch)) * 4096 + tid * 8;                        \
    __builtin_amdgcn_global_load_lds((AS1 const void*)_s, (AS3 void*)_d,        \
                                     16, 0, 0);                                 \
    __builtin_amdgcn_global_load_lds((AS1 const void*)(_s + (32 << 10)),        \
                                     (AS3 void*)(_d + 2048), 16, 0, 0);         \
  } while (0)

  // ds-read bases: A chunk = w>>1, B chunk = w&1 (row&7 == l15&7)
  int abase[4], bbase[4];
#pragma unroll
  for (int mi = 0; mi < 4; ++mi)
    abase[mi] = (w >> 1) * 4096 + (mi * 16 + l15) * 64;
#pragma unroll
  for (int ni = 0; ni < 4; ++ni)
    bbase[ni] = (2 + (w & 1)) * 4096 + (ni * 16 + l15) * 64;
  const int sw0 = ((quad ^ (l15 & 7)) << 3);
  const int sw1 = sw0 ^ 32;

  // prologue: kt0 {A0,A1,B0,B1} -> buf0; kt1 {A0,A1} -> buf1
  PSTAGEA(0, 0, 0); PSTAGEA(1, 0, 0);
  PSTAGEB(0, 0, 0); PSTAGEB(1, 0, 0);
  PSTAGEA(0, 1, BUFO); PSTAGEA(1, 1, BUFO);
  asm volatile("s_waitcnt vmcnt(4)" ::: "memory");  // kt0's 8 landed
  __builtin_amdgcn_s_barrier();

  f32x4 acc[4][4] = {};
  bf16x8 a[4][2], b[4][2];

#pragma unroll 2
  for (int j = 0; j < NT; ++j) {
    const int bo  = (j & 1) * BUFO;
    const int nbo = bo ^ BUFO;
    const u16* smb = sm + bo;

    // ---- phase 0: ds a(all) + b0,b1; stage B(j+1)->other; MFMA ni0-1
#pragma unroll
    for (int mi = 0; mi < 4; ++mi) {
      a[mi][0] = *(const bf16x8*)(smb + abase[mi] + sw0);
      a[mi][1] = *(const bf16x8*)(smb + abase[mi] + sw1);
    }
#pragma unroll
    for (int ni = 0; ni < 2; ++ni) {
      b[ni][0] = *(const bf16x8*)(smb + bbase[ni] + sw0);
      b[ni][1] = *(const bf16x8*)(smb + bbase[ni] + sw1);
    }
    if (j + 1 < NT) { PSTAGEB(0, j + 1, nbo); PSTAGEB(1, j + 1, nbo); }
    __builtin_amdgcn_s_barrier();
    asm volatile("s_waitcnt lgkmcnt(0)" ::: "memory");
    __builtin_amdgcn_s_setprio(1);
#pragma unroll
    for (int mi = 0; mi < 4; ++mi)
#pragma unroll
      for (int ni = 0; ni < 2; ++ni) {
        acc[mi][ni] = MFMA16(a[mi][0], b[ni][0], acc[mi][ni], 0, 0, 0);
        acc[mi][ni] = MFMA16(a[mi][1], b[ni][1], acc[mi][ni], 0, 0, 0);
      }
    __builtin_amdgcn_s_setprio(0);
    __builtin_amdgcn_s_barrier();
    // all A reads of buf j drained here

    // ---- phase 1: ds b2,b3; stage A(j+2)->cur; MFMA ni2-3; vmcnt(4)
#pragma unroll
    for (int ni = 2; ni < 4; ++ni) {
      b[ni][0] = *(const bf16x8*)(smb + bbase[ni] + sw0);
      b[ni][1] = *(const bf16x8*)(smb + bbase[ni] + sw1);
    }
    if (j + 2 < NT) { PSTAGEA(0, j + 2, bo); PSTAGEA(1, j + 2, bo); }
    __builtin_amdgcn_s_barrier();
    asm volatile("s_waitcnt lgkmcnt(0)" ::: "memory");
    __builtin_amdgcn_s_setprio(1);
#pragma unroll
    for (int mi = 0; mi < 4; ++mi)
#pragma unroll
      for (int ni = 2; ni < 4; ++ni) {
        acc[mi][ni] = MFMA16(a[mi][0], b[ni][0], acc[mi][ni], 0, 0, 0);
        acc[mi][ni] = MFMA16(a[mi][1], b[ni][1], acc[mi][ni], 0, 0, 0);
      }
    __builtin_amdgcn_s_setprio(0);
    if (j + 2 < NT)
      asm volatile("s_waitcnt vmcnt(4)" ::: "memory"); // (j+1) landed; A(j+2) fly
    else
      asm volatile("s_waitcnt vmcnt(0)" ::: "memory"); // tail drain
    __builtin_amdgcn_s_barrier();
  }
#undef PSTAGEA
#undef PSTAGEB

  const int crow0 = bm + wr + (quad << 2);
  const int ccol0 = bn + wcC + l15;
#pragma unroll
  for (int ni = 0; ni < 4; ++ni) {
    const int n = ccol0 + ni * 16;
    const float bv = bias[n];
#pragma unroll
    for (int mi = 0; mi < 4; ++mi) {
      const int m0 = crow0 + mi * 16;
#pragma unroll
      for (int r = 0; r < 4; ++r)
        C[(size_t)(m0 + r) * 1024 + n] = acc[mi][ni][r] + bv;
    }
  }
}

// ---------------- uniform-wave pipelined MFMA flash attention ---------------
// grid 1024 x 128 threads.  bid: xcd = bid&7 (4 bh per XCD, KV L2-resident);
// c = bid>>3: u = c&31 (q-group pair), bh = xcd | ((c>>5)<<3).
// Each wave: q-group 63-u fully, then q-group u (accO reused between groups).
// Parity waves split kt; per-wave total = 16-17 tiles UNIFORMLY across the
// whole grid -> 2 waves/SIMD resident for the entire kernel, no decay.
// K AND V prefetched depth-2 (kA/kB, vA/vB static ping-pong).
__global__ __launch_bounds__(128, 2) void attn_bal(const u16* __restrict__ qb,
                                                   const u16* __restrict__ KF,
                                                   const u16* __restrict__ VF,
                                                   u16* __restrict__ out) {
  const int bid = blockIdx.x;
  const int c   = bid >> 3;
  const int u   = c & 31;
  const int bh  = (bid & 7) | ((c >> 5) << 3);
  const int b = bh >> 4, h = bh & 15;
  const int tid = threadIdx.x;
  const int lane = tid & 63;
  const int par  = tid >> 6;          // wave 0/1 = kt parity
  const int quad = lane >> 4;
  const int l15  = lane & 15;

  __shared__ float CB[64][41];        // [lane][32 accO + 8 accL], stride 41

  const u16* qbase = qb + (size_t)b * 2048 * 1024 + h * 64;
  const size_t fb = (size_t)bh * 32 * 4096 + lane * 8;
  const u16* kfb = KF + fb;
  const u16* vfb = VF + fb;

  union { u32 u4[4]; bf16x8 v; } onesu;
  onesu.u4[0] = onesu.u4[1] = onesu.u4[2] = onesu.u4[3] = 0x3f803f80u;
  const bf16x8 onesf = onesu.v;       // bf16 1.0 x8

  u16* const outb = out + (size_t)b * 2048 * 1024 + h * 64 + l15;

  auto run_group = [&](int g32) {
    const int q0 = g32 * 32;
    const int ktmax = g32 >> 1;

    // Q B-frags for this group
    bf16x8 qf[2][2];
#pragma unroll
    for (int g = 0; g < 2; ++g)
#pragma unroll
      for (int hh = 0; hh < 2; ++hh)
        qf[g][hh] = *(const bf16x8*)(qbase + (size_t)(q0 + g * 16 + l15) * 1024 +
                                     hh * 32 + quad * 8);

    f32x4 accO[2][4] = {};            // [g][di]: q=quad*4+r, d=di*16+l15
    f32x4 accL[2] = {};               // [g]: l for q=quad*4+r

    // depth-2 K+V pipeline, two register sets (static ping-pong, no rotate)
    bf16x8 kA[4][2], kB[4][2], vA[2][4], vB[2][4];
    {
      const u16* kp = kfb + (size_t)par * 4096;
      const u16* vp = vfb + (size_t)par * 4096;
#pragma unroll
      for (int m = 0; m < 4; ++m)
#pragma unroll
        for (int hh = 0; hh < 2; ++hh)
          kA[m][hh] = *(const bf16x8*)(kp + (m * 2 + hh) * 512);
#pragma unroll
      for (int hh = 0; hh < 2; ++hh)
#pragma unroll
        for (int di = 0; di < 4; ++di)
          vA[hh][di] = *(const bf16x8*)(vp + (hh * 4 + di) * 512);
    }

    auto tile = [&](int kt, bf16x8 (&KC)[4][2], bf16x8 (&KN)[4][2],
                    bf16x8 (&VC)[2][4], bf16x8 (&VN)[2][4]) {
      // prefetch kt+2 (clamped) into the other register set
      const int ktn = (kt + 2 <= ktmax) ? kt + 2 : ktmax;
      const u16* kpn = kfb + (size_t)ktn * 4096;
      const u16* vpn = vfb + (size_t)ktn * 4096;
#pragma unroll
      for (int m = 0; m < 4; ++m)
#pragma unroll
        for (int hh = 0; hh < 2; ++hh)
          KN[m][hh] = *(const bf16x8*)(kpn + (m * 2 + hh) * 512);
#pragma unroll
      for (int hh = 0; hh < 2; ++hh)
#pragma unroll
        for (int di = 0; di < 4; ++di)
          VN[hh][di] = *(const bf16x8*)(vpn + (hh * 4 + di) * 512);

      const bool diag = (kt == ktmax);
      bf16x8 ap[2][2];
#pragma unroll
      for (int g = 0; g < 2; ++g) {
        f32x4 sT[4] = {};
#pragma unroll
        for (int m = 0; m < 4; ++m) {
          sT[m] = MFMA16(KC[m][0], qf[g][0], sT[m], 0, 0, 0);
          sT[m] = MFMA16(KC[m][1], qf[g][1], sT[m], 0, 0, 0);
        }
        float pv[4][4];
        if (diag) {                    // only the last tile pays mask ops
          const int qgl = q0 + g * 16 + l15;
#pragma unroll
          for (int m = 0; m < 4; ++m)
#pragma unroll
            for (int r = 0; r < 4; ++r) {
              const bool msk = (kt * 64 + m * 16 + quad * 4 + r) > qgl;
              pv[m][r] = msk ? 0.f : __builtin_amdgcn_exp2f(sT[m][r]);
            }
        } else {
#pragma unroll
          for (int m = 0; m < 4; ++m)
#pragma unroll
            for (int r = 0; r < 4; ++r)
              pv[m][r] = __builtin_amdgcn_exp2f(sT[m][r]);
        }
        union { u32 u4[4]; bf16x8 v; } t0, t1;
        t0.u4[0] = cvtpk(pv[0][0], pv[0][1]);
        t0.u4[1] = cvtpk(pv[0][2], pv[0][3]);
        t0.u4[2] = cvtpk(pv[1][0], pv[1][1]);
        t0.u4[3] = cvtpk(pv[1][2], pv[1][3]);
        t1.u4[0] = cvtpk(pv[2][0], pv[2][1]);
        t1.u4[1] = cvtpk(pv[2][2], pv[2][3]);
        t1.u4[2] = cvtpk(pv[3][0], pv[3][1]);
        t1.u4[3] = cvtpk(pv[3][2], pv[3][3]);
        ap[g][0] = t0.v;
        ap[g][1] = t1.v;
      }

      // O += P.V
#pragma unroll
      for (int hh = 0; hh < 2; ++hh)
#pragma unroll
        for (int di = 0; di < 4; ++di) {
          bf16x8 bv = VC[hh][di];
#pragma unroll
          for (int g = 0; g < 2; ++g)
            accO[g][di] = MFMA16(ap[g][hh], bv, accO[g][di], 0, 0, 0);
        }
      // l += P.1 (MFMA does the cross-quad k-reduction)
#pragma unroll
      for (int g = 0; g < 2; ++g) {
        accL[g] = MFMA16(ap[g][0], onesf, accL[g], 0, 0, 0);
        accL[g] = MFMA16(ap[g][1], onesf, accL[g], 0, 0, 0);
      }
    };

    for (int kt = par; kt <= ktmax; ) {
      tile(kt, kA, kB, vA, vB); kt += 2;
      if (kt > ktmax) break;
      tile(kt, kB, kA, vB, vA); kt += 2;
    }

    // ---- exact parity combine (per-lane values) ----
    if (par) {
      float* cb = CB[lane];
#pragma unroll
      for (int g = 0; g < 2; ++g) {
#pragma unroll
        for (int di = 0; di < 4; ++di)
#pragma unroll
          for (int r = 0; r < 4; ++r)
            cb[g * 16 + di * 4 + r] = accO[g][di][r];
#pragma unroll
        for (int r = 0; r < 4; ++r)
          cb[32 + g * 4 + r] = accL[g][r];
      }
    }
    __syncthreads();
    if (!par) {
      const float* cb = CB[lane];
#pragma unroll
      for (int g = 0; g < 2; ++g) {
#pragma unroll
        for (int di = 0; di < 4; ++di)
#pragma unroll
          for (int r = 0; r < 4; ++r)
            accO[g][di][r] += cb[g * 16 + di * 4 + r];
#pragma unroll
        for (int r = 0; r < 4; ++r)
          accL[g][r] += cb[32 + g * 4 + r];
      }
#pragma unroll
      for (int g = 0; g < 2; ++g)
#pragma unroll
        for (int r = 0; r < 4; ++r) {
          const float inv = 1.f / accL[g][r]; // lane holds l for its own rows
          const int q = q0 + g * 16 + quad * 4 + r;
          u16* op = outb + (size_t)q * 1024;
#pragma unroll
          for (int di = 0; di < 4; ++di)
            op[di * 16] = f2bf(accO[g][di][r] * inv);
        }
    }
    __syncthreads();   // CB safe for reuse by the next group
  };

  run_group(63 - u);   // heavy half
  run_group(u);        // light half -> every wave totals 16-17 tiles
}

// ---------------------------------------------------------------------------
extern "C" void kernel_launch(void* const* d_in, const int* in_sizes, int n_in,
                              void* d_out, int out_size, void* d_ws, size_t ws_size,
                              hipStream_t stream) {
  const float* x     = (const float*)d_in[0];
  const float* Wqkv  = (const float*)d_in[1];
  const float* bqkv  = (const float*)d_in[2];
  const float* Wproj = (const float*)d_in[3];
  const float* bproj = (const float*)d_in[4];
  float* out = (float*)d_out;

  char* ws = (char*)d_ws;
  u16* xb     = (u16*)(ws);                 //  8 MB  x bf16 [4096,1024]
  u16* wqkvT  = (u16*)(ws + 8388608);       //  6 MB  Wqkv^T bf16 [3072,1024]
  u16* wprojT = (u16*)(ws + 14680064);      //  2 MB  Wproj^T bf16 [1024,1024]
  u16* qb     = (u16*)(ws + 16777216);      //  8 MB  Q bf16 [4096,1024] (pre-scaled)
  u16* KF     = (u16*)(ws + 25165824);      //  8 MB  K fragment-order
  u16* VF     = (u16*)(ws + 33554432);      //  8 MB  V fragment-order (k-perm)
  u16* att    = (u16*)(ws + 41943040);      //  8 MB  attn out bf16 [4096,1024]

  constexpr float cs = 0.18033688011f;      // log2(e)/8

  prep<<<8192, 256, 0, stream>>>(x, xb, Wqkv, wqkvT, Wproj, wprojT);

  gemm_qkv<<<dim3(256), 512, 0, stream>>>(xb, wqkvT, bqkv, qb, KF, VF, cs);

  attn_bal<<<dim3(1024), 128, 0, stream>>>(qb, KF, VF, att);

  gemm_proj<<<dim3(256), 256, 0, stream>>>(att, wprojT, bproj, out);
}

// Round 6
// 154.785 us; speedup vs baseline: 1.0872x; 1.0090x over previous
//
#include <hip/hip_runtime.h>
#include <hip/hip_bf16.h>
#include <cstdint>

// ---------------------------------------------------------------------------
// CausalSelfAttention: x@Wqkv+b -> heads -> causal flash attn -> @Wproj+b
// B=2 T=2048 C=1024 H=16 Dh=64.
// R16: gemm_qkv + gemm_proj K-loops collapsed to ONE phase per K-tile.
//  - R15 post-mortem: qkv runs 1 block/CU (112KB LDS), 2 waves/SIMD barrier-
//    locked to the same phase -> ds_read time and MFMA time ADD (6 barriers/
//    K-tile). MfmaUtil 19.5% ~= MFMA/(MFMA+LDS+stall).
//  - New body: issue all 22 ds_reads; stage A2A3(j+1)->other; lgkmcnt(10)
//    (first 12 = alo+b01 done, rest complete UNDER MFMA grp0); lgkmcnt(0);
//    barrier (all reads of buf j drained); stage 5 chunks (j+2)->CURRENT buf
//    (safe: reads retired); MFMA grp1+grp2 (register-only, run over the
//    staging writes); vmcnt(5); barrier.  2 barriers/K-tile instead of 6.
//  - Compiler guarantees ds_read->MFMA waits (C++-level loads); asm waits +
//    sched_barrier(0) are schedule pins (rule: hipcc may hoist reg-only MFMA
//    past inline-asm waitcnt).
//  - Same transform on gemm_proj: 16 reads, lgkmcnt(4) split, 2 barriers.
// R14 (kept): attn uniform-wave (63-u then u per wave), K+V depth-2 ping-
//  pong, l via ones-MFMA, cvt_pk pack. R12 (kept): swizzle (conflicts 0),
//  counted vmcnt, XCD maps, full coverage.
// HARD-WON NOTES:
//  - R7: forcing low VGPR (launch_bounds 256,4) -> catastrophic spills.
//  - R13: VGPR>128 cliff; occupancy-DECAY from non-uniform blocks dominates.
//  - R11: partial-coverage grids idle CUs; coverage before tile size.
// ---------------------------------------------------------------------------

using u16 = unsigned short;
using u32 = unsigned int;

typedef __bf16 bf16x8 __attribute__((ext_vector_type(8)));
typedef float f32x4 __attribute__((ext_vector_type(4)));

#define AS1 __attribute__((address_space(1)))
#define AS3 __attribute__((address_space(3)))

__device__ __forceinline__ u16 f2bf(float f) {
  u32 u = __float_as_uint(f);
  u += 0x7fffu + ((u >> 16) & 1u);   // RTNE
  return (u16)(u >> 16);
}
__device__ __forceinline__ u32 cvtpk(float a, float b) {
  u32 r;
  asm("v_cvt_pk_bf16_f32 %0, %1, %2" : "=v"(r) : "v"(a), "v"(b));
  return r;
}

// ---------------- prep: cvt x->bf16 (blocks 0..4095) + W transposes ---------
__global__ __launch_bounds__(256) void prep(const float* __restrict__ x,
                                            u16* __restrict__ xb,
                                            const float* __restrict__ W0,
                                            u16* __restrict__ T0,
                                            const float* __restrict__ W1,
                                            u16* __restrict__ T1) {
  const int bx = blockIdx.x;
  const int tid = threadIdx.x;
  if (bx < 4096) {
    const int i = bx * 256 + tid;
    float4 v = ((const float4*)x)[i];
    ushort4 o;
    o.x = f2bf(v.x); o.y = f2bf(v.y); o.z = f2bf(v.z); o.w = f2bf(v.w);
    ((ushort4*)xb)[i] = o;
    return;
  }
  __shared__ float t[32][33];
  const int idx = bx - 4096;          // 128 n-tiles x 32 k-tiles
  const int bxx = idx & 127, by = idx >> 7;
  const float* W; u16* Wt; int N, n0;
  if (bxx < 96) { W = W0; Wt = T0; N = 3072; n0 = bxx * 32; }
  else          { W = W1; Wt = T1; N = 1024; n0 = (bxx - 96) * 32; }
  const int k0 = by * 32;
  const int tx = tid & 31, ty = tid >> 5;
#pragma unroll
  for (int i = 0; i < 4; ++i)
    t[ty + i * 8][tx] = W[(size_t)(k0 + ty + i * 8) * N + n0 + tx];
  __syncthreads();
#pragma unroll
  for (int i = 0; i < 4; ++i)
    Wt[(size_t)(n0 + ty + i * 8) * 1024 + k0 + tx] = f2bf(t[tx][ty + i * 8]);
}

// ---------------- QKV GEMM: 256x192, 1-phase overlapped K-loop --------------
// n<1024: Q (scaled by cs) -> qb[4096][1024]
// 1024<=n<2048: K -> KF fragment order [bh][kt][m][hh][lane][8]
// n>=2048:     V -> VF fragment order [bh][kt][hh][di][lane][8] (k-permuted)
#define MFMA16 __builtin_amdgcn_mfma_f32_16x16x32_bf16

__global__ __launch_bounds__(512, 2) void gemm_qkv(const u16* __restrict__ A,
                                                   const u16* __restrict__ Bt,
                                                   const float* __restrict__ bias,
                                                   u16* __restrict__ qb,
                                                   u16* __restrict__ KF,
                                                   u16* __restrict__ VF,
                                                   float sc_val) {
  constexpr int NT = 16;                    // K=1024 / BK=64
  constexpr int BUFO = 7 * 4096;            // u16 per buffer (7 chunks)
  __shared__ __align__(16) u16 sm[2 * BUFO];  // 112 KiB

  const int tid  = threadIdx.x;
  const int lane = tid & 63;
  const int w    = tid >> 6;          // 0..7
  const int quad = lane >> 4;
  const int l15  = lane & 15;

  // block -> tile: XCD-bijective (256 blocks = 8 XCD x 32), 4x8 region/XCD
  const int bid = blockIdx.x;
  const int xcd = bid & 7, c = bid >> 3;         // c 0..31
  const int mt = (xcd >> 1) * 4 + (c & 3);       // 0..15
  const int nt = (xcd & 1) * 8 + (c >> 2);       // 0..15
  const int bm = mt * 256, bn = nt * 192;

  const int wr = (w >> 2) * 128;      // wave rows (0/128)
  const int wc = (w & 3) * 48;        // wave cols (0/48/96/144)

  // ---- staging: thread writes 16B linearly at chunk + tid*16.
  // LDS row = tid>>3, granule = tid&7; source granule = (tid&7)^(row&7).
  const int srow = tid >> 3;
  const int scol = (((tid & 7) ^ ((tid >> 3) & 7)) << 3);

#define STAGEA(ch, ktile, bufo)                                                 \
  __builtin_amdgcn_global_load_lds(                                             \
      (AS1 const void*)(A + (size_t)(bm + (ch) * 64 + srow) * 1024 +            \
                        ((ktile) << 6) + scol),                                 \
      (AS3 void*)(sm + (bufo) + (ch) * 4096 + tid * 8), 16, 0, 0)
#define STAGEB(ch, ktile, bufo)                                                 \
  __builtin_amdgcn_global_load_lds(                                             \
      (AS1 const void*)(Bt + (size_t)(bn + (ch) * 64 + srow) * 1024 +           \
                        ((ktile) << 6) + scol),                                 \
      (AS3 void*)(sm + (bufo) + (4 + (ch)) * 4096 + tid * 8), 16, 0, 0)

  // ---- ds-read bases (swizzled granule; row&7 == l15&7 everywhere)
  const int ca = (w >> 2) * 2;        // A chunk base: 0 or 2
  int abase_lo[4], abase_hi[4], bbase[3];
#pragma unroll
  for (int mi = 0; mi < 4; ++mi) {
    abase_lo[mi] = (ca + 0) * 4096 + (mi * 16 + l15) * 64;
    abase_hi[mi] = (ca + 1) * 4096 + (mi * 16 + l15) * 64;
  }
#pragma unroll
  for (int ni = 0; ni < 3; ++ni) {
    const int rb = wc + ni * 16 + l15;            // 0..191
    bbase[ni] = (4 + (rb >> 6)) * 4096 + (rb & 63) * 64;
  }
  const int sw0 = ((quad ^ (l15 & 7)) << 3);
  const int sw1 = sw0 ^ 32;

  // ---- prologue: kt0 all 7 -> buf0; kt1 B0B1,B2,A0A1 -> buf1
  STAGEA(0, 0, 0); STAGEA(1, 0, 0); STAGEA(2, 0, 0); STAGEA(3, 0, 0);
  STAGEB(0, 0, 0); STAGEB(1, 0, 0); STAGEB(2, 0, 0);
  STAGEB(0, 1, BUFO); STAGEB(1, 1, BUFO);
  STAGEB(2, 1, BUFO); STAGEA(0, 1, BUFO); STAGEA(1, 1, BUFO);
  asm volatile("s_waitcnt vmcnt(5)" ::: "memory");  // kt0 landed; kt1's 5 fly
  __builtin_amdgcn_s_barrier();

  f32x4 acc[8][3] = {};
  bf16x8 alo[4][2], ahi[4][2], b[3][2];

#pragma unroll 2
  for (int j = 0; j < NT; ++j) {
    const int bo  = (j & 1) * BUFO;
    const int nbo = bo ^ BUFO;
    const u16* smb = sm + bo;

    // ---- issue ALL 22 ds_reads for this K-tile (buffer fully landed) ----
#pragma unroll
    for (int mi = 0; mi < 4; ++mi) {
      alo[mi][0] = *(const bf16x8*)(smb + abase_lo[mi] + sw0);
      alo[mi][1] = *(const bf16x8*)(smb + abase_lo[mi] + sw1);
    }
#pragma unroll
    for (int ni = 0; ni < 2; ++ni) {
      b[ni][0] = *(const bf16x8*)(smb + bbase[ni] + sw0);
      b[ni][1] = *(const bf16x8*)(smb + bbase[ni] + sw1);
    }
#pragma unroll
    for (int mi = 0; mi < 4; ++mi) {
      ahi[mi][0] = *(const bf16x8*)(smb + abase_hi[mi] + sw0);
      ahi[mi][1] = *(const bf16x8*)(smb + abase_hi[mi] + sw1);
    }
    b[2][0] = *(const bf16x8*)(smb + bbase[2] + sw0);
    b[2][1] = *(const bf16x8*)(smb + bbase[2] + sw1);
    // stage A2A3(j+1) -> other buffer (its chunks drained at end of j-1)
    if (j + 1 < NT) { STAGEA(2, j + 1, nbo); STAGEA(3, j + 1, nbo); }

    asm volatile("s_waitcnt lgkmcnt(10)" ::: "memory");  // alo+b01 landed
    __builtin_amdgcn_sched_barrier(0);
    __builtin_amdgcn_s_setprio(1);
    // MFMA grp0: alo x b01 (reads 13-22 complete underneath)
#pragma unroll
    for (int mi = 0; mi < 4; ++mi)
#pragma unroll
      for (int ni = 0; ni < 2; ++ni) {
        acc[mi][ni] = MFMA16(alo[mi][0], b[ni][0], acc[mi][ni], 0, 0, 0);
        acc[mi][ni] = MFMA16(alo[mi][1], b[ni][1], acc[mi][ni], 0, 0, 0);
      }
    __builtin_amdgcn_s_setprio(0);
    asm volatile("s_waitcnt lgkmcnt(0)" ::: "memory");   // all 22 landed
    __builtin_amdgcn_sched_barrier(0);
    __builtin_amdgcn_s_barrier();     // every wave done READING buf j
    // stage (j+2) -> CURRENT buffer (safe: all reads retired to registers)
    if (j + 2 < NT) {
      STAGEB(0, j + 2, bo); STAGEB(1, j + 2, bo); STAGEB(2, j + 2, bo);
      STAGEA(0, j + 2, bo); STAGEA(1, j + 2, bo);
    }
    __builtin_amdgcn_s_setprio(1);
    // MFMA grp1+grp2 (register-only; runs over the staging writes)
#pragma unroll
    for (int mi = 0; mi < 4; ++mi) {
      acc[mi][2] = MFMA16(alo[mi][0], b[2][0], acc[mi][2], 0, 0, 0);
      acc[mi][2] = MFMA16(alo[mi][1], b[2][1], acc[mi][2], 0, 0, 0);
      acc[4 + mi][0] = MFMA16(ahi[mi][0], b[0][0], acc[4 + mi][0], 0, 0, 0);
      acc[4 + mi][0] = MFMA16(ahi[mi][1], b[0][1], acc[4 + mi][0], 0, 0, 0);
    }
#pragma unroll
    for (int mi = 0; mi < 4; ++mi)
#pragma unroll
      for (int ni = 1; ni < 3; ++ni) {
        acc[4 + mi][ni] = MFMA16(ahi[mi][0], b[ni][0], acc[4 + mi][ni], 0, 0, 0);
        acc[4 + mi][ni] = MFMA16(ahi[mi][1], b[ni][1], acc[4 + mi][ni], 0, 0, 0);
      }
    __builtin_amdgcn_s_setprio(0);
    if (j + 2 < NT)
      asm volatile("s_waitcnt vmcnt(5)" ::: "memory"); // drains A2A3(j+1)+older
    else
      asm volatile("s_waitcnt vmcnt(0)" ::: "memory"); // tail drain
    __builtin_amdgcn_s_barrier();
  }
#undef STAGEA
#undef STAGEB

  // ---- epilogue: per-ni region branch (192-wide blocks straddle Q/K/V) ----
  const int crow0 = bm + wr + (quad << 2);
  const int ccol0 = bn + wc + l15;
#pragma unroll
  for (int ni = 0; ni < 3; ++ni) {
    const int n = ccol0 + ni * 16;
    const float bv = bias[n];
    if (n < 1024) {                     // ---- Q (scaled) ----
#pragma unroll
      for (int mi = 0; mi < 8; ++mi) {
        const int m0 = crow0 + mi * 16;
#pragma unroll
        for (int r = 0; r < 4; ++r)
          qb[(size_t)(m0 + r) * 1024 + n] = f2bf((acc[mi][ni][r] + bv) * sc_val);
      }
    } else if (n < 2048) {              // ---- K fragment order ----
      const int hk = (n - 1024) >> 6;
      const int d  = (n - 1024) & 63;
      const int hh = d >> 5, qd = (d >> 3) & 3, jj = d & 7;
#pragma unroll
      for (int mi = 0; mi < 8; ++mi) {
#pragma unroll
        for (int r = 0; r < 4; ++r) {
          const int t  = crow0 + mi * 16 + r;
          const int bb = t >> 11, tt = t & 2047;
          const int kt = tt >> 6, mm = (tt >> 4) & 3, l = tt & 15;
          KF[((size_t)((bb * 16 + hk) * 32 + kt) * 8 + mm * 2 + hh) * 512 +
             (qd * 16 + l) * 8 + jj] = f2bf(acc[mi][ni][r] + bv);
        }
      }
    } else {                            // ---- V fragment order (k-perm) ----
      const int hv = (n - 2048) >> 6;
      const int d  = (n - 2048) & 63;
      const int di = d >> 4, l = d & 15;
#pragma unroll
      for (int mi = 0; mi < 8; ++mi) {
#pragma unroll
        for (int r = 0; r < 4; ++r) {
          const int t  = crow0 + mi * 16 + r;
          const int bb = t >> 11, tt = t & 2047;
          const int kt = tt >> 6, to = tt & 63;
          const int mq = to >> 4, qd2 = (to >> 2) & 3, rr = to & 3;
          const int hh = mq >> 1, jj = (mq & 1) * 4 + rr;
          VF[((size_t)((bb * 16 + hv) * 32 + kt) * 8 + hh * 4 + di) * 512 +
             (qd2 * 16 + l) * 8 + jj] = f2bf(acc[mi][ni][r] + bv);
        }
      }
    }
  }
}

// ---------------- Proj GEMM: 128x128, BK=64, 1-phase overlapped -------------
// M=4096 N=1024 K=1024, fp32 out.  256 blocks (32 mt x 8 nt), 256 thr.
// 4 waves @ 64x64 (acc[4][4]).  LDS 2 bufs x {A0,A1,B0,B1} [64][64] = 64 KiB.
__global__ __launch_bounds__(256, 2) void gemm_proj(const u16* __restrict__ A,
                                                    const u16* __restrict__ Bt,
                                                    const float* __restrict__ bias,
                                                    float* __restrict__ C) {
  constexpr int NT = 16;                    // K=1024 / BK=64
  constexpr int BUFO = 4 * 4096;            // u16 per buffer (4 chunks)
  __shared__ __align__(16) u16 sm[2 * BUFO];  // 64 KiB

  const int tid  = threadIdx.x;
  const int lane = tid & 63;
  const int w    = tid >> 6;          // 0..3
  const int quad = lane >> 4;
  const int l15  = lane & 15;

  // 256 blocks = 8 XCD x 32: each XCD owns 4 consecutive mt x all 8 nt
  const int bid = blockIdx.x;
  const int xcd = bid & 7, c = bid >> 3;     // c 0..31
  const int mt = xcd * 4 + (c & 3);          // 0..31
  const int nt = c >> 2;                     // 0..7
  const int bm = mt * 128, bn = nt * 128;

  const int wr = (w >> 1) * 64;       // wave rows (0/64)
  const int wcC = (w & 1) * 64;       // wave cols (0/64)

  // staging: thread covers row tid>>3 (and +32), granule tid&7 (swizzled src)
  const int srow = tid >> 3;
  const int scol = (((tid & 7) ^ ((tid >> 3) & 7)) << 3);

#define PSTAGEA(ch, ktile, bufo)                                                \
  do {                                                                          \
    const u16* _s = A + (size_t)(bm + (ch) * 64 + srow) * 1024 +                \
                    ((ktile) << 6) + scol;                                      \
    u16* _d = sm + (bufo) + (ch) * 4096 + tid * 8;                              \
    __builtin_amdgcn_global_load_lds((AS1 const void*)_s, (AS3 void*)_d,        \
                                     16, 0, 0);                                 \
    __builtin_amdgcn_global_load_lds((AS1 const void*)(_s + (32 << 10)),        \
                                     (AS3 void*)(_d + 2048), 16, 0, 0);         \
  } while (0)
#define PSTAGEB(ch, ktile, bufo)                                                \
  do {                                                                          \
    const u16* _s = Bt + (size_t)(bn + (ch) * 64 + srow) * 1024 +               \
                    ((ktile) << 6) + scol;                                      \
    u16* _d = sm + (bufo) + (2 + (ch)) * 4096 + tid * 8;                        \
    __builtin_amdgcn_global_load_lds((AS1 const void*)_s, (AS3 void*)_d,        \
                                     16, 0, 0);                                 \
    __builtin_amdgcn_global_load_lds((AS1 const void*)(_s + (32 << 10)),        \
                                     (AS3 void*)(_d + 2048), 16, 0, 0);         \
  } while (0)

  // ds-read bases: A chunk = w>>1, B chunk = w&1 (row&7 == l15&7)
  int abase[4], bbase[4];
#pragma unroll
  for (int mi = 0; mi < 4; ++mi)
    abase[mi] = (w >> 1) * 4096 + (mi * 16 + l15) * 64;
#pragma unroll
  for (int ni = 0; ni < 4; ++ni)
    bbase[ni] = (2 + (w & 1)) * 4096 + (ni * 16 + l15) * 64;
  const int sw0 = ((quad ^ (l15 & 7)) << 3);
  const int sw1 = sw0 ^ 32;

  // prologue: kt0 {A0,A1,B0,B1} -> buf0; kt1 {A0,A1} -> buf1
  PSTAGEA(0, 0, 0); PSTAGEA(1, 0, 0);
  PSTAGEB(0, 0, 0); PSTAGEB(1, 0, 0);
  PSTAGEA(0, 1, BUFO); PSTAGEA(1, 1, BUFO);
  asm volatile("s_waitcnt vmcnt(4)" ::: "memory");  // kt0's 8 landed
  __builtin_amdgcn_s_barrier();

  f32x4 acc[4][4] = {};
  bf16x8 a[4][2], b[4][2];

#pragma unroll 2
  for (int j = 0; j < NT; ++j) {
    const int bo  = (j & 1) * BUFO;
    const int nbo = bo ^ BUFO;
    const u16* smb = sm + bo;

    // ---- issue ALL 16 ds_reads; stage B(j+1)->other ----
#pragma unroll
    for (int mi = 0; mi < 4; ++mi) {
      a[mi][0] = *(const bf16x8*)(smb + abase[mi] + sw0);
      a[mi][1] = *(const bf16x8*)(smb + abase[mi] + sw1);
    }
#pragma unroll
    for (int ni = 0; ni < 2; ++ni) {
      b[ni][0] = *(const bf16x8*)(smb + bbase[ni] + sw0);
      b[ni][1] = *(const bf16x8*)(smb + bbase[ni] + sw1);
    }
#pragma unroll
    for (int ni = 2; ni < 4; ++ni) {
      b[ni][0] = *(const bf16x8*)(smb + bbase[ni] + sw0);
      b[ni][1] = *(const bf16x8*)(smb + bbase[ni] + sw1);
    }
    if (j + 1 < NT) { PSTAGEB(0, j + 1, nbo); PSTAGEB(1, j + 1, nbo); }

    asm volatile("s_waitcnt lgkmcnt(4)" ::: "memory");   // a + b01 landed
    __builtin_amdgcn_sched_barrier(0);
    __builtin_amdgcn_s_setprio(1);
#pragma unroll
    for (int mi = 0; mi < 4; ++mi)
#pragma unroll
      for (int ni = 0; ni < 2; ++ni) {
        acc[mi][ni] = MFMA16(a[mi][0], b[ni][0], acc[mi][ni], 0, 0, 0);
        acc[mi][ni] = MFMA16(a[mi][1], b[ni][1], acc[mi][ni], 0, 0, 0);
      }
    __builtin_amdgcn_s_setprio(0);
    asm volatile("s_waitcnt lgkmcnt(0)" ::: "memory");   // all 16 landed
    __builtin_amdgcn_sched_barrier(0);
    __builtin_amdgcn_s_barrier();     // every wave done READING buf j
    if (j + 2 < NT) { PSTAGEA(0, j + 2, bo); PSTAGEA(1, j + 2, bo); }
    __builtin_amdgcn_s_setprio(1);
#pragma unroll
    for (int mi = 0; mi < 4; ++mi)
#pragma unroll
      for (int ni = 2; ni < 4; ++ni) {
        acc[mi][ni] = MFMA16(a[mi][0], b[ni][0], acc[mi][ni], 0, 0, 0);
        acc[mi][ni] = MFMA16(a[mi][1], b[ni][1], acc[mi][ni], 0, 0, 0);
      }
    __builtin_amdgcn_s_setprio(0);
    if (j + 2 < NT)
      asm volatile("s_waitcnt vmcnt(4)" ::: "memory"); // (j+1) landed; A(j+2) fly
    else
      asm volatile("s_waitcnt vmcnt(0)" ::: "memory"); // tail drain
    __builtin_amdgcn_s_barrier();
  }
#undef PSTAGEA
#undef PSTAGEB

  const int crow0 = bm + wr + (quad << 2);
  const int ccol0 = bn + wcC + l15;
#pragma unroll
  for (int ni = 0; ni < 4; ++ni) {
    const int n = ccol0 + ni * 16;
    const float bv = bias[n];
#pragma unroll
    for (int mi = 0; mi < 4; ++mi) {
      const int m0 = crow0 + mi * 16;
#pragma unroll
      for (int r = 0; r < 4; ++r)
        C[(size_t)(m0 + r) * 1024 + n] = acc[mi][ni][r] + bv;
    }
  }
}

// ---------------- uniform-wave pipelined MFMA flash attention ---------------
// grid 1024 x 128 threads.  bid: xcd = bid&7 (4 bh per XCD, KV L2-resident);
// c = bid>>3: u = c&31 (q-group pair), bh = xcd | ((c>>5)<<3).
// Each wave: q-group 63-u fully, then q-group u (accO reused between groups).
// Parity waves split kt; per-wave total = 16-17 tiles UNIFORMLY across the
// whole grid -> 2 waves/SIMD resident for the entire kernel, no decay.
// K AND V prefetched depth-2 (kA/kB, vA/vB static ping-pong).
__global__ __launch_bounds__(128, 2) void attn_bal(const u16* __restrict__ qb,
                                                   const u16* __restrict__ KF,
                                                   const u16* __restrict__ VF,
                                                   u16* __restrict__ out) {
  const int bid = blockIdx.x;
  const int c   = bid >> 3;
  const int u   = c & 31;
  const int bh  = (bid & 7) | ((c >> 5) << 3);
  const int b = bh >> 4, h = bh & 15;
  const int tid = threadIdx.x;
  const int lane = tid & 63;
  const int par  = tid >> 6;          // wave 0/1 = kt parity
  const int quad = lane >> 4;
  const int l15  = lane & 15;

  __shared__ float CB[64][41];        // [lane][32 accO + 8 accL], stride 41

  const u16* qbase = qb + (size_t)b * 2048 * 1024 + h * 64;
  const size_t fb = (size_t)bh * 32 * 4096 + lane * 8;
  const u16* kfb = KF + fb;
  const u16* vfb = VF + fb;

  union { u32 u4[4]; bf16x8 v; } onesu;
  onesu.u4[0] = onesu.u4[1] = onesu.u4[2] = onesu.u4[3] = 0x3f803f80u;
  const bf16x8 onesf = onesu.v;       // bf16 1.0 x8

  u16* const outb = out + (size_t)b * 2048 * 1024 + h * 64 + l15;

  auto run_group = [&](int g32) {
    const int q0 = g32 * 32;
    const int ktmax = g32 >> 1;

    // Q B-frags for this group
    bf16x8 qf[2][2];
#pragma unroll
    for (int g = 0; g < 2; ++g)
#pragma unroll
      for (int hh = 0; hh < 2; ++hh)
        qf[g][hh] = *(const bf16x8*)(qbase + (size_t)(q0 + g * 16 + l15) * 1024 +
                                     hh * 32 + quad * 8);

    f32x4 accO[2][4] = {};            // [g][di]: q=quad*4+r, d=di*16+l15
    f32x4 accL[2] = {};               // [g]: l for q=quad*4+r

    // depth-2 K+V pipeline, two register sets (static ping-pong, no rotate)
    bf16x8 kA[4][2], kB[4][2], vA[2][4], vB[2][4];
    {
      const u16* kp = kfb + (size_t)par * 4096;
      const u16* vp = vfb + (size_t)par * 4096;
#pragma unroll
      for (int m = 0; m < 4; ++m)
#pragma unroll
        for (int hh = 0; hh < 2; ++hh)
          kA[m][hh] = *(const bf16x8*)(kp + (m * 2 + hh) * 512);
#pragma unroll
      for (int hh = 0; hh < 2; ++hh)
#pragma unroll
        for (int di = 0; di < 4; ++di)
          vA[hh][di] = *(const bf16x8*)(vp + (hh * 4 + di) * 512);
    }

    auto tile = [&](int kt, bf16x8 (&KC)[4][2], bf16x8 (&KN)[4][2],
                    bf16x8 (&VC)[2][4], bf16x8 (&VN)[2][4]) {
      // prefetch kt+2 (clamped) into the other register set
      const int ktn = (kt + 2 <= ktmax) ? kt + 2 : ktmax;
      const u16* kpn = kfb + (size_t)ktn * 4096;
      const u16* vpn = vfb + (size_t)ktn * 4096;
#pragma unroll
      for (int m = 0; m < 4; ++m)
#pragma unroll
        for (int hh = 0; hh < 2; ++hh)
          KN[m][hh] = *(const bf16x8*)(kpn + (m * 2 + hh) * 512);
#pragma unroll
      for (int hh = 0; hh < 2; ++hh)
#pragma unroll
        for (int di = 0; di < 4; ++di)
          VN[hh][di] = *(const bf16x8*)(vpn + (hh * 4 + di) * 512);

      const bool diag = (kt == ktmax);
      bf16x8 ap[2][2];
#pragma unroll
      for (int g = 0; g < 2; ++g) {
        f32x4 sT[4] = {};
#pragma unroll
        for (int m = 0; m < 4; ++m) {
          sT[m] = MFMA16(KC[m][0], qf[g][0], sT[m], 0, 0, 0);
          sT[m] = MFMA16(KC[m][1], qf[g][1], sT[m], 0, 0, 0);
        }
        float pv[4][4];
        if (diag) {                    // only the last tile pays mask ops
          const int qgl = q0 + g * 16 + l15;
#pragma unroll
          for (int m = 0; m < 4; ++m)
#pragma unroll
            for (int r = 0; r < 4; ++r) {
              const bool msk = (kt * 64 + m * 16 + quad * 4 + r) > qgl;
              pv[m][r] = msk ? 0.f : __builtin_amdgcn_exp2f(sT[m][r]);
            }
        } else {
#pragma unroll
          for (int m = 0; m < 4; ++m)
#pragma unroll
            for (int r = 0; r < 4; ++r)
              pv[m][r] = __builtin_amdgcn_exp2f(sT[m][r]);
        }
        union { u32 u4[4]; bf16x8 v; } t0, t1;
        t0.u4[0] = cvtpk(pv[0][0], pv[0][1]);
        t0.u4[1] = cvtpk(pv[0][2], pv[0][3]);
        t0.u4[2] = cvtpk(pv[1][0], pv[1][1]);
        t0.u4[3] = cvtpk(pv[1][2], pv[1][3]);
        t1.u4[0] = cvtpk(pv[2][0], pv[2][1]);
        t1.u4[1] = cvtpk(pv[2][2], pv[2][3]);
        t1.u4[2] = cvtpk(pv[3][0], pv[3][1]);
        t1.u4[3] = cvtpk(pv[3][2], pv[3][3]);
        ap[g][0] = t0.v;
        ap[g][1] = t1.v;
      }

      // O += P.V
#pragma unroll
      for (int hh = 0; hh < 2; ++hh)
#pragma unroll
        for (int di = 0; di < 4; ++di) {
          bf16x8 bv = VC[hh][di];
#pragma unroll
          for (int g = 0; g < 2; ++g)
            accO[g][di] = MFMA16(ap[g][hh], bv, accO[g][di], 0, 0, 0);
        }
      // l += P.1 (MFMA does the cross-quad k-reduction)
#pragma unroll
      for (int g = 0; g < 2; ++g) {
        accL[g] = MFMA16(ap[g][0], onesf, accL[g], 0, 0, 0);
        accL[g] = MFMA16(ap[g][1], onesf, accL[g], 0, 0, 0);
      }
    };

    for (int kt = par; kt <= ktmax; ) {
      tile(kt, kA, kB, vA, vB); kt += 2;
      if (kt > ktmax) break;
      tile(kt, kB, kA, vB, vA); kt += 2;
    }

    // ---- exact parity combine (per-lane values) ----
    if (par) {
      float* cb = CB[lane];
#pragma unroll
      for (int g = 0; g < 2; ++g) {
#pragma unroll
        for (int di = 0; di < 4; ++di)
#pragma unroll
          for (int r = 0; r < 4; ++r)
            cb[g * 16 + di * 4 + r] = accO[g][di][r];
#pragma unroll
        for (int r = 0; r < 4; ++r)
          cb[32 + g * 4 + r] = accL[g][r];
      }
    }
    __syncthreads();
    if (!par) {
      const float* cb = CB[lane];
#pragma unroll
      for (int g = 0; g < 2; ++g) {
#pragma unroll
        for (int di = 0; di < 4; ++di)
#pragma unroll
          for (int r = 0; r < 4; ++r)
            accO[g][di][r] += cb[g * 16 + di * 4 + r];
#pragma unroll
        for (int r = 0; r < 4; ++r)
          accL[g][r] += cb[32 + g * 4 + r];
      }
#pragma unroll
      for (int g = 0; g < 2; ++g)
#pragma unroll
        for (int r = 0; r < 4; ++r) {
          const float inv = 1.f / accL[g][r]; // lane holds l for its own rows
          const int q = q0 + g * 16 + quad * 4 + r;
          u16* op = outb + (size_t)q * 1024;
#pragma unroll
          for (int di = 0; di < 4; ++di)
            op[di * 16] = f2bf(accO[g][di][r] * inv);
        }
    }
    __syncthreads();   // CB safe for reuse by the next group
  };

  run_group(63 - u);   // heavy half
  run_group(u);        // light half -> every wave totals 16-17 tiles
}

// ---------------------------------------------------------------------------
extern "C" void kernel_launch(void* const* d_in, const int* in_sizes, int n_in,
                              void* d_out, int out_size, void* d_ws, size_t ws_size,
                              hipStream_t stream) {
  const float* x     = (const float*)d_in[0];
  const float* Wqkv  = (const float*)d_in[1];
  const float* bqkv  = (const float*)d_in[2];
  const float* Wproj = (const float*)d_in[3];
  const float* bproj = (const float*)d_in[4];
  float* out = (float*)d_out;

  char* ws = (char*)d_ws;
  u16* xb     = (u16*)(ws);                 //  8 MB  x bf16 [4096,1024]
  u16* wqkvT  = (u16*)(ws + 8388608);       //  6 MB  Wqkv^T bf16 [3072,1024]
  u16* wprojT = (u16*)(ws + 14680064);      //  2 MB  Wproj^T bf16 [1024,1024]
  u16* qb     = (u16*)(ws + 16777216);      //  8 MB  Q bf16 [4096,1024] (pre-scaled)
  u16* KF     = (u16*)(ws + 25165824);      //  8 MB  K fragment-order
  u16* VF     = (u16*)(ws + 33554432);      //  8 MB  V fragment-order (k-perm)
  u16* att    = (u16*)(ws + 41943040);      //  8 MB  attn out bf16 [4096,1024]

  constexpr float cs = 0.18033688011f;      // log2(e)/8

  prep<<<8192, 256, 0, stream>>>(x, xb, Wqkv, wqkvT, Wproj, wprojT);

  gemm_qkv<<<dim3(256), 512, 0, stream>>>(xb, wqkvT, bqkv, qb, KF, VF, cs);

  attn_bal<<<dim3(1024), 128, 0, stream>>>(qb, KF, VF, att);

  gemm_proj<<<dim3(256), 256, 0, stream>>>(att, wprojT, bproj, out);
}

// Round 7
// 149.581 us; speedup vs baseline: 1.1250x; 1.0348x over previous
//
#include <hip/hip_runtime.h>
#include <hip/hip_bf16.h>
#include <cstdint>

// ---------------------------------------------------------------------------
// CausalSelfAttention: x@Wqkv+b -> heads -> causal flash attn -> @Wproj+b
// B=2 T=2048 C=1024 H=16 Dh=64.
// R17: BOTH GEMMs restructured for 2 independently-phased blocks per CU.
//  - R15/R16 post-mortem: two different schedules (3-phase, 1-phase) both
//    landed ~41-45us. Shared invariant = 1 block/CU, all waves barrier-locked
//    in the same phase -> LDS-read bursts and MFMA bursts ADD. m114: separate
//    blocks co-scheduled on a CU overlap (time = max). Fix = occupancy 2.
//  - gemm_qkv: BM=128 BN=192 BK=64, 256thr (4 waves @ 128x48, acc[8][3]),
//    LDS 2buf x 5 chunks [64][64] = 80KB -> exactly 2 blocks/CU. grid 512.
//    1-phase body (R16): 22 ds_reads; stage B012(j+1)->other at top; lgkm(10)
//    -> MFMA grp0 (alo x b01); lgkm(0); barrier; stage A01(j+2)->cur; MFMA
//    grp1 (reg-only, over staging); vmcnt(4); barrier.
//    vmcnt(4) at end of tile j: outstanding = [A(j+1):4, end j-1][B(j+1):6,
//    top j][A(j+2):4, end j] = 14 -> drains A(j+1)+B(j+1) => buf j+1 fully
//    landed before tile j+1 reads. Prologue: kt0 all5 -> buf0, A01(kt1) ->
//    buf1, vmcnt(4).
//  - gemm_proj: BM=128 BN=64, 256thr (4 waves @ 64x32), LDS 48KB, grid 512
//    = 2/CU (was 256 = 1 block/CU = 1 wave/SIMD!). Same schedule, vmcnt(4),
//    lgkmcnt(2) split.
// R14 (kept): attn uniform-wave (63-u then u), K+V depth-2 ping-pong,
//  l via ones-MFMA, cvt_pk pack. R12 (kept): granule XOR-swizzle (conflicts
//  3.1M->0), inverse-swizzled global source, XCD maps.
// HARD-WON NOTES:
//  - R7: forcing low VGPR (launch_bounds 256,4) -> catastrophic spills.
//  - R13: VGPR>128 cliff halves waves; occupancy-DECAY from non-uniform
//    block lengths dominates per-tile thinning.
//  - R11: partial-coverage grids idle CUs; coverage before tile size.
//  - R15/R16: schedule tuning inside ONE barrier-locked block is futile;
//    independent co-resident blocks are what overlap mem and MFMA phases.
// ---------------------------------------------------------------------------

using u16 = unsigned short;
using u32 = unsigned int;

typedef __bf16 bf16x8 __attribute__((ext_vector_type(8)));
typedef float f32x4 __attribute__((ext_vector_type(4)));

#define AS1 __attribute__((address_space(1)))
#define AS3 __attribute__((address_space(3)))

__device__ __forceinline__ u16 f2bf(float f) {
  u32 u = __float_as_uint(f);
  u += 0x7fffu + ((u >> 16) & 1u);   // RTNE
  return (u16)(u >> 16);
}
__device__ __forceinline__ u32 cvtpk(float a, float b) {
  u32 r;
  asm("v_cvt_pk_bf16_f32 %0, %1, %2" : "=v"(r) : "v"(a), "v"(b));
  return r;
}

// ---------------- prep: cvt x->bf16 (blocks 0..4095) + W transposes ---------
__global__ __launch_bounds__(256) void prep(const float* __restrict__ x,
                                            u16* __restrict__ xb,
                                            const float* __restrict__ W0,
                                            u16* __restrict__ T0,
                                            const float* __restrict__ W1,
                                            u16* __restrict__ T1) {
  const int bx = blockIdx.x;
  const int tid = threadIdx.x;
  if (bx < 4096) {
    const int i = bx * 256 + tid;
    float4 v = ((const float4*)x)[i];
    ushort4 o;
    o.x = f2bf(v.x); o.y = f2bf(v.y); o.z = f2bf(v.z); o.w = f2bf(v.w);
    ((ushort4*)xb)[i] = o;
    return;
  }
  __shared__ float t[32][33];
  const int idx = bx - 4096;          // 128 n-tiles x 32 k-tiles
  const int bxx = idx & 127, by = idx >> 7;
  const float* W; u16* Wt; int N, n0;
  if (bxx < 96) { W = W0; Wt = T0; N = 3072; n0 = bxx * 32; }
  else          { W = W1; Wt = T1; N = 1024; n0 = (bxx - 96) * 32; }
  const int k0 = by * 32;
  const int tx = tid & 31, ty = tid >> 5;
#pragma unroll
  for (int i = 0; i < 4; ++i)
    t[ty + i * 8][tx] = W[(size_t)(k0 + ty + i * 8) * N + n0 + tx];
  __syncthreads();
#pragma unroll
  for (int i = 0; i < 4; ++i)
    Wt[(size_t)(n0 + ty + i * 8) * 1024 + k0 + tx] = f2bf(t[tx][ty + i * 8]);
}

// ---------------- QKV GEMM: 128x192, 2 blocks/CU, 1-phase -------------------
// n<1024: Q (scaled by cs) -> qb[4096][1024]
// 1024<=n<2048: K -> KF fragment order [bh][kt][m][hh][lane][8]
// n>=2048:     V -> VF fragment order [bh][kt][hh][di][lane][8] (k-permuted)
#define MFMA16 __builtin_amdgcn_mfma_f32_16x16x32_bf16

__global__ __launch_bounds__(256, 2) void gemm_qkv(const u16* __restrict__ A,
                                                   const u16* __restrict__ Bt,
                                                   const float* __restrict__ bias,
                                                   u16* __restrict__ qb,
                                                   u16* __restrict__ KF,
                                                   u16* __restrict__ VF,
                                                   float sc_val) {
  constexpr int NT = 16;                    // K=1024 / BK=64
  constexpr int BUFO = 5 * 4096;            // u16 per buffer (A0,A1,B0,B1,B2)
  __shared__ __align__(16) u16 sm[2 * BUFO];  // 80 KiB -> 2 blocks/CU

  const int tid  = threadIdx.x;
  const int lane = tid & 63;
  const int w    = tid >> 6;          // 0..3
  const int quad = lane >> 4;
  const int l15  = lane & 15;

  // block -> tile: 512 blocks = 8 XCD x 64; each XCD: 4 mt x 16 nt
  const int bid = blockIdx.x;
  const int xcd = bid & 7, c = bid >> 3;     // c 0..63
  const int mt = xcd * 4 + (c & 3);          // 0..31
  const int nt = c >> 2;                     // 0..15
  const int bm = mt * 128, bn = nt * 192;

  const int wc = w * 48;              // wave cols; all waves share rows 0..127

  // ---- staging: 256 thr; chunk [64][64] u16 = 8KB -> 2 issues (rows 0-31,
  // 32-63). LDS row = tid>>3 (+32), granule tid&7; src granule pre-swizzled.
  const int srow = tid >> 3;          // 0..31
  const int scol = (((tid & 7) ^ ((tid >> 3) & 7)) << 3);  // (32&7)==0: same

#define STAGEA(ch, ktile, bufo)                                                 \
  do {                                                                          \
    const u16* _s = A + (size_t)(bm + (ch) * 64 + srow) * 1024 +                \
                    ((ktile) << 6) + scol;                                      \
    u16* _d = sm + (bufo) + (ch) * 4096 + tid * 8;                              \
    __builtin_amdgcn_global_load_lds((AS1 const void*)_s, (AS3 void*)_d,        \
                                     16, 0, 0);                                 \
    __builtin_amdgcn_global_load_lds((AS1 const void*)(_s + (32 << 10)),        \
                                     (AS3 void*)(_d + 2048), 16, 0, 0);         \
  } while (0)
#define STAGEB(ch, ktile, bufo)                                                 \
  do {                                                                          \
    const u16* _s = Bt + (size_t)(bn + (ch) * 64 + srow) * 1024 +               \
                    ((ktile) << 6) + scol;                                      \
    u16* _d = sm + (bufo) + (2 + (ch)) * 4096 + tid * 8;                        \
    __builtin_amdgcn_global_load_lds((AS1 const void*)_s, (AS3 void*)_d,        \
                                     16, 0, 0);                                 \
    __builtin_amdgcn_global_load_lds((AS1 const void*)(_s + (32 << 10)),        \
                                     (AS3 void*)(_d + 2048), 16, 0, 0);         \
  } while (0)

  // ---- ds-read bases (swizzled granule; row&7 == l15&7 everywhere)
  int abase_lo[4], abase_hi[4], bbase[3];
#pragma unroll
  for (int mi = 0; mi < 4; ++mi) {
    abase_lo[mi] = 0 * 4096 + (mi * 16 + l15) * 64;     // rows 0..63
    abase_hi[mi] = 1 * 4096 + (mi * 16 + l15) * 64;     // rows 64..127
  }
#pragma unroll
  for (int ni = 0; ni < 3; ++ni) {
    const int rb = wc + ni * 16 + l15;                  // 0..191
    bbase[ni] = (2 + (rb >> 6)) * 4096 + (rb & 63) * 64;
  }
  const int sw0 = ((quad ^ (l15 & 7)) << 3);
  const int sw1 = sw0 ^ 32;

  // ---- prologue: kt0 all 5 -> buf0 (10 issues); A01(kt1) -> buf1 (4)
  STAGEA(0, 0, 0); STAGEA(1, 0, 0);
  STAGEB(0, 0, 0); STAGEB(1, 0, 0); STAGEB(2, 0, 0);
  STAGEA(0, 1, BUFO); STAGEA(1, 1, BUFO);
  asm volatile("s_waitcnt vmcnt(4)" ::: "memory");  // kt0's 10 landed
  __builtin_amdgcn_s_barrier();

  f32x4 acc[8][3] = {};
  bf16x8 alo[4][2], ahi[4][2], b[3][2];

#pragma unroll 2
  for (int j = 0; j < NT; ++j) {
    const int bo  = (j & 1) * BUFO;
    const int nbo = bo ^ BUFO;
    const u16* smb = sm + bo;

    // ---- issue ALL 22 ds_reads (buf j fully landed at this point) ----
#pragma unroll
    for (int mi = 0; mi < 4; ++mi) {
      alo[mi][0] = *(const bf16x8*)(smb + abase_lo[mi] + sw0);
      alo[mi][1] = *(const bf16x8*)(smb + abase_lo[mi] + sw1);
    }
#pragma unroll
    for (int ni = 0; ni < 2; ++ni) {
      b[ni][0] = *(const bf16x8*)(smb + bbase[ni] + sw0);
      b[ni][1] = *(const bf16x8*)(smb + bbase[ni] + sw1);
    }
#pragma unroll
    for (int mi = 0; mi < 4; ++mi) {
      ahi[mi][0] = *(const bf16x8*)(smb + abase_hi[mi] + sw0);
      ahi[mi][1] = *(const bf16x8*)(smb + abase_hi[mi] + sw1);
    }
    b[2][0] = *(const bf16x8*)(smb + bbase[2] + sw0);
    b[2][1] = *(const bf16x8*)(smb + bbase[2] + sw1);
    // stage B(j+1) -> other buffer (its B chunks drained in tile j-1)
    if (j + 1 < NT) { STAGEB(0, j + 1, nbo); STAGEB(1, j + 1, nbo); STAGEB(2, j + 1, nbo); }

    asm volatile("s_waitcnt lgkmcnt(10)" ::: "memory");  // alo+b01 (12) landed
    __builtin_amdgcn_sched_barrier(0);
    __builtin_amdgcn_s_setprio(1);
    // MFMA grp0: alo x b01 (reads 13-22 complete underneath)
#pragma unroll
    for (int mi = 0; mi < 4; ++mi)
#pragma unroll
      for (int ni = 0; ni < 2; ++ni) {
        acc[mi][ni] = MFMA16(alo[mi][0], b[ni][0], acc[mi][ni], 0, 0, 0);
        acc[mi][ni] = MFMA16(alo[mi][1], b[ni][1], acc[mi][ni], 0, 0, 0);
      }
    __builtin_amdgcn_s_setprio(0);
    asm volatile("s_waitcnt lgkmcnt(0)" ::: "memory");   // all 22 landed
    __builtin_amdgcn_sched_barrier(0);
    __builtin_amdgcn_s_barrier();     // every wave done READING buf j
    // stage A(j+2) -> CURRENT buffer (safe: reads retired to registers)
    if (j + 2 < NT) { STAGEA(0, j + 2, bo); STAGEA(1, j + 2, bo); }
    __builtin_amdgcn_s_setprio(1);
    // MFMA grp1 (register-only; runs over the staging writes)
#pragma unroll
    for (int mi = 0; mi < 4; ++mi) {
      acc[mi][2] = MFMA16(alo[mi][0], b[2][0], acc[mi][2], 0, 0, 0);
      acc[mi][2] = MFMA16(alo[mi][1], b[2][1], acc[mi][2], 0, 0, 0);
      acc[4 + mi][0] = MFMA16(ahi[mi][0], b[0][0], acc[4 + mi][0], 0, 0, 0);
      acc[4 + mi][0] = MFMA16(ahi[mi][1], b[0][1], acc[4 + mi][0], 0, 0, 0);
    }
#pragma unroll
    for (int mi = 0; mi < 4; ++mi)
#pragma unroll
      for (int ni = 1; ni < 3; ++ni) {
        acc[4 + mi][ni] = MFMA16(ahi[mi][0], b[ni][0], acc[4 + mi][ni], 0, 0, 0);
        acc[4 + mi][ni] = MFMA16(ahi[mi][1], b[ni][1], acc[4 + mi][ni], 0, 0, 0);
      }
    __builtin_amdgcn_s_setprio(0);
    if (j + 2 < NT)
      asm volatile("s_waitcnt vmcnt(4)" ::: "memory"); // A(j+1)+B(j+1) landed
    else
      asm volatile("s_waitcnt vmcnt(0)" ::: "memory"); // tail drain
    __builtin_amdgcn_s_barrier();
  }
#undef STAGEA
#undef STAGEB

  // ---- epilogue: per-ni region branch (192-wide blocks straddle Q/K/V) ----
  const int crow0 = bm + (quad << 2);
  const int ccol0 = bn + wc + l15;
#pragma unroll
  for (int ni = 0; ni < 3; ++ni) {
    const int n = ccol0 + ni * 16;
    const float bv = bias[n];
    if (n < 1024) {                     // ---- Q (scaled) ----
#pragma unroll
      for (int mi = 0; mi < 8; ++mi) {
        const int m0 = crow0 + mi * 16;
#pragma unroll
        for (int r = 0; r < 4; ++r)
          qb[(size_t)(m0 + r) * 1024 + n] = f2bf((acc[mi][ni][r] + bv) * sc_val);
      }
    } else if (n < 2048) {              // ---- K fragment order ----
      const int hk = (n - 1024) >> 6;
      const int d  = (n - 1024) & 63;
      const int hh = d >> 5, qd = (d >> 3) & 3, jj = d & 7;
#pragma unroll
      for (int mi = 0; mi < 8; ++mi) {
#pragma unroll
        for (int r = 0; r < 4; ++r) {
          const int t  = crow0 + mi * 16 + r;
          const int bb = t >> 11, tt = t & 2047;
          const int kt = tt >> 6, mm = (tt >> 4) & 3, l = tt & 15;
          KF[((size_t)((bb * 16 + hk) * 32 + kt) * 8 + mm * 2 + hh) * 512 +
             (qd * 16 + l) * 8 + jj] = f2bf(acc[mi][ni][r] + bv);
        }
      }
    } else {                            // ---- V fragment order (k-perm) ----
      const int hv = (n - 2048) >> 6;
      const int d  = (n - 2048) & 63;
      const int di = d >> 4, l = d & 15;
#pragma unroll
      for (int mi = 0; mi < 8; ++mi) {
#pragma unroll
        for (int r = 0; r < 4; ++r) {
          const int t  = crow0 + mi * 16 + r;
          const int bb = t >> 11, tt = t & 2047;
          const int kt = tt >> 6, to = tt & 63;
          const int mq = to >> 4, qd2 = (to >> 2) & 3, rr = to & 3;
          const int hh = mq >> 1, jj = (mq & 1) * 4 + rr;
          VF[((size_t)((bb * 16 + hv) * 32 + kt) * 8 + hh * 4 + di) * 512 +
             (qd2 * 16 + l) * 8 + jj] = f2bf(acc[mi][ni][r] + bv);
        }
      }
    }
  }
}

// ---------------- Proj GEMM: 128x64, 2 blocks/CU, 1-phase -------------------
// M=4096 N=1024 K=1024, fp32 out.  512 blocks (32 mt x 16 nt), 256 thr,
// 4 waves @ 64x32 (acc[4][2]).  LDS 2 bufs x {A0,A1,B0} = 48 KiB.
__global__ __launch_bounds__(256, 2) void gemm_proj(const u16* __restrict__ A,
                                                    const u16* __restrict__ Bt,
                                                    const float* __restrict__ bias,
                                                    float* __restrict__ C) {
  constexpr int NT = 16;                    // K=1024 / BK=64
  constexpr int BUFO = 3 * 4096;            // u16 per buffer (A0,A1,B0)
  __shared__ __align__(16) u16 sm[2 * BUFO];  // 48 KiB

  const int tid  = threadIdx.x;
  const int lane = tid & 63;
  const int w    = tid >> 6;          // 0..3
  const int quad = lane >> 4;
  const int l15  = lane & 15;

  // 512 blocks = 8 XCD x 64: each XCD 4 mt x 16 nt
  const int bid = blockIdx.x;
  const int xcd = bid & 7, c = bid >> 3;     // c 0..63
  const int mt = xcd * 4 + (c & 3);          // 0..31
  const int nt = c >> 2;                     // 0..15
  const int bm = mt * 128, bn = nt * 64;

  const int wr = (w >> 1) * 64;       // wave rows (0/64)
  const int wcC = (w & 1) * 32;       // wave cols (0/32)

  const int srow = tid >> 3;
  const int scol = (((tid & 7) ^ ((tid >> 3) & 7)) << 3);

#define PSTAGEA(ch, ktile, bufo)                                                \
  do {                                                                          \
    const u16* _s = A + (size_t)(bm + (ch) * 64 + srow) * 1024 +                \
                    ((ktile) << 6) + scol;                                      \
    u16* _d = sm + (bufo) + (ch) * 4096 + tid * 8;                              \
    __builtin_amdgcn_global_load_lds((AS1 const void*)_s, (AS3 void*)_d,        \
                                     16, 0, 0);                                 \
    __builtin_amdgcn_global_load_lds((AS1 const void*)(_s + (32 << 10)),        \
                                     (AS3 void*)(_d + 2048), 16, 0, 0);         \
  } while (0)
#define PSTAGEB(ktile, bufo)                                                    \
  do {                                                                          \
    const u16* _s = Bt + (size_t)(bn + srow) * 1024 + ((ktile) << 6) + scol;    \
    u16* _d = sm + (bufo) + 2 * 4096 + tid * 8;                                 \
    __builtin_amdgcn_global_load_lds((AS1 const void*)_s, (AS3 void*)_d,        \
                                     16, 0, 0);                                 \
    __builtin_amdgcn_global_load_lds((AS1 const void*)(_s + (32 << 10)),        \
                                     (AS3 void*)(_d + 2048), 16, 0, 0);         \
  } while (0)

  // ds-read bases: A chunk = w>>1; B rows wcC + ni*16 + l15 in chunk 2
  int abase[4], bbase[2];
#pragma unroll
  for (int mi = 0; mi < 4; ++mi)
    abase[mi] = (w >> 1) * 4096 + (mi * 16 + l15) * 64;
#pragma unroll
  for (int ni = 0; ni < 2; ++ni)
    bbase[ni] = 2 * 4096 + (wcC + ni * 16 + l15) * 64;
  const int sw0 = ((quad ^ (l15 & 7)) << 3);
  const int sw1 = sw0 ^ 32;

  // prologue: kt0 {A0,A1,B0} -> buf0 (6); A01(kt1) -> buf1 (4)
  PSTAGEA(0, 0, 0); PSTAGEA(1, 0, 0); PSTAGEB(0, 0);
  PSTAGEA(0, 1, BUFO); PSTAGEA(1, 1, BUFO);
  asm volatile("s_waitcnt vmcnt(4)" ::: "memory");  // kt0's 6 landed
  __builtin_amdgcn_s_barrier();

  f32x4 acc[4][2] = {};
  bf16x8 a[4][2], b[2][2];

#pragma unroll 2
  for (int j = 0; j < NT; ++j) {
    const int bo  = (j & 1) * BUFO;
    const int nbo = bo ^ BUFO;
    const u16* smb = sm + bo;

    // ---- issue ALL 12 ds_reads; stage B(j+1)->other ----
#pragma unroll
    for (int mi = 0; mi < 4; ++mi) {
      a[mi][0] = *(const bf16x8*)(smb + abase[mi] + sw0);
      a[mi][1] = *(const bf16x8*)(smb + abase[mi] + sw1);
    }
#pragma unroll
    for (int ni = 0; ni < 2; ++ni) {
      b[ni][0] = *(const bf16x8*)(smb + bbase[ni] + sw0);
      b[ni][1] = *(const bf16x8*)(smb + bbase[ni] + sw1);
    }
    if (j + 1 < NT) PSTAGEB(j + 1, nbo);

    asm volatile("s_waitcnt lgkmcnt(2)" ::: "memory");   // a + b0 landed
    __builtin_amdgcn_sched_barrier(0);
    __builtin_amdgcn_s_setprio(1);
#pragma unroll
    for (int mi = 0; mi < 4; ++mi) {
      acc[mi][0] = MFMA16(a[mi][0], b[0][0], acc[mi][0], 0, 0, 0);
      acc[mi][0] = MFMA16(a[mi][1], b[0][1], acc[mi][0], 0, 0, 0);
    }
    __builtin_amdgcn_s_setprio(0);
    asm volatile("s_waitcnt lgkmcnt(0)" ::: "memory");   // all 12 landed
    __builtin_amdgcn_sched_barrier(0);
    __builtin_amdgcn_s_barrier();     // every wave done READING buf j
    if (j + 2 < NT) { PSTAGEA(0, j + 2, bo); PSTAGEA(1, j + 2, bo); }
    __builtin_amdgcn_s_setprio(1);
#pragma unroll
    for (int mi = 0; mi < 4; ++mi) {
      acc[mi][1] = MFMA16(a[mi][0], b[1][0], acc[mi][1], 0, 0, 0);
      acc[mi][1] = MFMA16(a[mi][1], b[1][1], acc[mi][1], 0, 0, 0);
    }
    __builtin_amdgcn_s_setprio(0);
    if (j + 2 < NT)
      asm volatile("s_waitcnt vmcnt(4)" ::: "memory"); // A(j+1)+B(j+1) landed
    else
      asm volatile("s_waitcnt vmcnt(0)" ::: "memory"); // tail drain
    __builtin_amdgcn_s_barrier();
  }
#undef PSTAGEA
#undef PSTAGEB

  const int crow0 = bm + wr + (quad << 2);
  const int ccol0 = bn + wcC + l15;
#pragma unroll
  for (int ni = 0; ni < 2; ++ni) {
    const int n = ccol0 + ni * 16;
    const float bv = bias[n];
#pragma unroll
    for (int mi = 0; mi < 4; ++mi) {
      const int m0 = crow0 + mi * 16;
#pragma unroll
      for (int r = 0; r < 4; ++r)
        C[(size_t)(m0 + r) * 1024 + n] = acc[mi][ni][r] + bv;
    }
  }
}

// ---------------- uniform-wave pipelined MFMA flash attention ---------------
// grid 1024 x 128 threads.  bid: xcd = bid&7 (4 bh per XCD, KV L2-resident);
// c = bid>>3: u = c&31 (q-group pair), bh = xcd | ((c>>5)<<3).
// Each wave: q-group 63-u fully, then q-group u (accO reused between groups).
// Parity waves split kt; per-wave total = 16-17 tiles UNIFORMLY across the
// whole grid -> 2 waves/SIMD resident for the entire kernel, no decay.
// K AND V prefetched depth-2 (kA/kB, vA/vB static ping-pong).
__global__ __launch_bounds__(128, 2) void attn_bal(const u16* __restrict__ qb,
                                                   const u16* __restrict__ KF,
                                                   const u16* __restrict__ VF,
                                                   u16* __restrict__ out) {
  const int bid = blockIdx.x;
  const int c   = bid >> 3;
  const int u   = c & 31;
  const int bh  = (bid & 7) | ((c >> 5) << 3);
  const int b = bh >> 4, h = bh & 15;
  const int tid = threadIdx.x;
  const int lane = tid & 63;
  const int par  = tid >> 6;          // wave 0/1 = kt parity
  const int quad = lane >> 4;
  const int l15  = lane & 15;

  __shared__ float CB[64][41];        // [lane][32 accO + 8 accL], stride 41

  const u16* qbase = qb + (size_t)b * 2048 * 1024 + h * 64;
  const size_t fb = (size_t)bh * 32 * 4096 + lane * 8;
  const u16* kfb = KF + fb;
  const u16* vfb = VF + fb;

  union { u32 u4[4]; bf16x8 v; } onesu;
  onesu.u4[0] = onesu.u4[1] = onesu.u4[2] = onesu.u4[3] = 0x3f803f80u;
  const bf16x8 onesf = onesu.v;       // bf16 1.0 x8

  u16* const outb = out + (size_t)b * 2048 * 1024 + h * 64 + l15;

  auto run_group = [&](int g32) {
    const int q0 = g32 * 32;
    const int ktmax = g32 >> 1;

    // Q B-frags for this group
    bf16x8 qf[2][2];
#pragma unroll
    for (int g = 0; g < 2; ++g)
#pragma unroll
      for (int hh = 0; hh < 2; ++hh)
        qf[g][hh] = *(const bf16x8*)(qbase + (size_t)(q0 + g * 16 + l15) * 1024 +
                                     hh * 32 + quad * 8);

    f32x4 accO[2][4] = {};            // [g][di]: q=quad*4+r, d=di*16+l15
    f32x4 accL[2] = {};               // [g]: l for q=quad*4+r

    // depth-2 K+V pipeline, two register sets (static ping-pong, no rotate)
    bf16x8 kA[4][2], kB[4][2], vA[2][4], vB[2][4];
    {
      const u16* kp = kfb + (size_t)par * 4096;
      const u16* vp = vfb + (size_t)par * 4096;
#pragma unroll
      for (int m = 0; m < 4; ++m)
#pragma unroll
        for (int hh = 0; hh < 2; ++hh)
          kA[m][hh] = *(const bf16x8*)(kp + (m * 2 + hh) * 512);
#pragma unroll
      for (int hh = 0; hh < 2; ++hh)
#pragma unroll
        for (int di = 0; di < 4; ++di)
          vA[hh][di] = *(const bf16x8*)(vp + (hh * 4 + di) * 512);
    }

    auto tile = [&](int kt, bf16x8 (&KC)[4][2], bf16x8 (&KN)[4][2],
                    bf16x8 (&VC)[2][4], bf16x8 (&VN)[2][4]) {
      // prefetch kt+2 (clamped) into the other register set
      const int ktn = (kt + 2 <= ktmax) ? kt + 2 : ktmax;
      const u16* kpn = kfb + (size_t)ktn * 4096;
      const u16* vpn = vfb + (size_t)ktn * 4096;
#pragma unroll
      for (int m = 0; m < 4; ++m)
#pragma unroll
        for (int hh = 0; hh < 2; ++hh)
          KN[m][hh] = *(const bf16x8*)(kpn + (m * 2 + hh) * 512);
#pragma unroll
      for (int hh = 0; hh < 2; ++hh)
#pragma unroll
        for (int di = 0; di < 4; ++di)
          VN[hh][di] = *(const bf16x8*)(vpn + (hh * 4 + di) * 512);

      const bool diag = (kt == ktmax);
      bf16x8 ap[2][2];
#pragma unroll
      for (int g = 0; g < 2; ++g) {
        f32x4 sT[4] = {};
#pragma unroll
        for (int m = 0; m < 4; ++m) {
          sT[m] = MFMA16(KC[m][0], qf[g][0], sT[m], 0, 0, 0);
          sT[m] = MFMA16(KC[m][1], qf[g][1], sT[m], 0, 0, 0);
        }
        float pv[4][4];
        if (diag) {                    // only the last tile pays mask ops
          const int qgl = q0 + g * 16 + l15;
#pragma unroll
          for (int m = 0; m < 4; ++m)
#pragma unroll
            for (int r = 0; r < 4; ++r) {
              const bool msk = (kt * 64 + m * 16 + quad * 4 + r) > qgl;
              pv[m][r] = msk ? 0.f : __builtin_amdgcn_exp2f(sT[m][r]);
            }
        } else {
#pragma unroll
          for (int m = 0; m < 4; ++m)
#pragma unroll
            for (int r = 0; r < 4; ++r)
              pv[m][r] = __builtin_amdgcn_exp2f(sT[m][r]);
        }
        union { u32 u4[4]; bf16x8 v; } t0, t1;
        t0.u4[0] = cvtpk(pv[0][0], pv[0][1]);
        t0.u4[1] = cvtpk(pv[0][2], pv[0][3]);
        t0.u4[2] = cvtpk(pv[1][0], pv[1][1]);
        t0.u4[3] = cvtpk(pv[1][2], pv[1][3]);
        t1.u4[0] = cvtpk(pv[2][0], pv[2][1]);
        t1.u4[1] = cvtpk(pv[2][2], pv[2][3]);
        t1.u4[2] = cvtpk(pv[3][0], pv[3][1]);
        t1.u4[3] = cvtpk(pv[3][2], pv[3][3]);
        ap[g][0] = t0.v;
        ap[g][1] = t1.v;
      }

      // O += P.V
#pragma unroll
      for (int hh = 0; hh < 2; ++hh)
#pragma unroll
        for (int di = 0; di < 4; ++di) {
          bf16x8 bv = VC[hh][di];
#pragma unroll
          for (int g = 0; g < 2; ++g)
            accO[g][di] = MFMA16(ap[g][hh], bv, accO[g][di], 0, 0, 0);
        }
      // l += P.1 (MFMA does the cross-quad k-reduction)
#pragma unroll
      for (int g = 0; g < 2; ++g) {
        accL[g] = MFMA16(ap[g][0], onesf, accL[g], 0, 0, 0);
        accL[g] = MFMA16(ap[g][1], onesf, accL[g], 0, 0, 0);
      }
    };

    for (int kt = par; kt <= ktmax; ) {
      tile(kt, kA, kB, vA, vB); kt += 2;
      if (kt > ktmax) break;
      tile(kt, kB, kA, vB, vA); kt += 2;
    }

    // ---- exact parity combine (per-lane values) ----
    if (par) {
      float* cb = CB[lane];
#pragma unroll
      for (int g = 0; g < 2; ++g) {
#pragma unroll
        for (int di = 0; di < 4; ++di)
#pragma unroll
          for (int r = 0; r < 4; ++r)
            cb[g * 16 + di * 4 + r] = accO[g][di][r];
#pragma unroll
        for (int r = 0; r < 4; ++r)
          cb[32 + g * 4 + r] = accL[g][r];
      }
    }
    __syncthreads();
    if (!par) {
      const float* cb = CB[lane];
#pragma unroll
      for (int g = 0; g < 2; ++g) {
#pragma unroll
        for (int di = 0; di < 4; ++di)
#pragma unroll
          for (int r = 0; r < 4; ++r)
            accO[g][di][r] += cb[g * 16 + di * 4 + r];
#pragma unroll
        for (int r = 0; r < 4; ++r)
          accL[g][r] += cb[32 + g * 4 + r];
      }
#pragma unroll
      for (int g = 0; g < 2; ++g)
#pragma unroll
        for (int r = 0; r < 4; ++r) {
          const float inv = 1.f / accL[g][r]; // lane holds l for its own rows
          const int q = q0 + g * 16 + quad * 4 + r;
          u16* op = outb + (size_t)q * 1024;
#pragma unroll
          for (int di = 0; di < 4; ++di)
            op[di * 16] = f2bf(accO[g][di][r] * inv);
        }
    }
    __syncthreads();   // CB safe for reuse by the next group
  };

  run_group(63 - u);   // heavy half
  run_group(u);        // light half -> every wave totals 16-17 tiles
}

// ---------------------------------------------------------------------------
extern "C" void kernel_launch(void* const* d_in, const int* in_sizes, int n_in,
                              void* d_out, int out_size, void* d_ws, size_t ws_size,
                              hipStream_t stream) {
  const float* x     = (const float*)d_in[0];
  const float* Wqkv  = (const float*)d_in[1];
  const float* bqkv  = (const float*)d_in[2];
  const float* Wproj = (const float*)d_in[3];
  const float* bproj = (const float*)d_in[4];
  float* out = (float*)d_out;

  char* ws = (char*)d_ws;
  u16* xb     = (u16*)(ws);                 //  8 MB  x bf16 [4096,1024]
  u16* wqkvT  = (u16*)(ws + 8388608);       //  6 MB  Wqkv^T bf16 [3072,1024]
  u16* wprojT = (u16*)(ws + 14680064);      //  2 MB  Wproj^T bf16 [1024,1024]
  u16* qb     = (u16*)(ws + 16777216);      //  8 MB  Q bf16 [4096,1024] (pre-scaled)
  u16* KF     = (u16*)(ws + 25165824);      //  8 MB  K fragment-order
  u16* VF     = (u16*)(ws + 33554432);      //  8 MB  V fragment-order (k-perm)
  u16* att    = (u16*)(ws + 41943040);      //  8 MB  attn out bf16 [4096,1024]

  constexpr float cs = 0.18033688011f;      // log2(e)/8

  prep<<<8192, 256, 0, stream>>>(x, xb, Wqkv, wqkvT, Wproj, wprojT);

  gemm_qkv<<<dim3(512), 256, 0, stream>>>(xb, wqkvT, bqkv, qb, KF, VF, cs);

  attn_bal<<<dim3(1024), 128, 0, stream>>>(qb, KF, VF, att);

  gemm_proj<<<dim3(512), 256, 0, stream>>>(att, wprojT, bproj, out);
}